// Round 21
// baseline (203.522 us; speedup 1.0000x reference)
//
#include <hip/hip_runtime.h>
#include <hip/hip_bf16.h>
#include <cstdint>

#define T_TOK 8192
#define HID   1024
#define NE    9
#define ISZ   512
#define RBASE 18432
#define NSLOT (RBASE + T_TOK)   // 26624

#define BM 256
#define NROWB (NSLOT / BM)      // 104

typedef unsigned short u16;
typedef unsigned int   u32;
typedef signed char    i8;
typedef __attribute__((ext_vector_type(8))) short short8;
typedef __attribute__((ext_vector_type(4))) float f32x4;
typedef __attribute__((ext_vector_type(4))) int   i32x4;

__device__ __forceinline__ u16 f2bf(float f) {
  u32 u = __builtin_bit_cast(u32, f);
  return (u16)((u + 0x7fffu + ((u >> 16) & 1u)) >> 16);
}
__device__ __forceinline__ float bf2f(u16 v) {
  return __builtin_bit_cast(float, (u32)v << 16);
}
__device__ __forceinline__ int q8(float v, float inv) {
  int q = (int)__builtin_rintf(v * inv);
  return (q > 127) ? 127 : ((q < -127) ? -127 : q);
}
__device__ __forceinline__ int colp_of(int c) {
  int i = (c < 512) ? c : (c - 512);
  return (i >> 4) * 32 + ((c < 512) ? 0 : 16) + (i & 15);
}

#define STAGE(gp, lp) __builtin_amdgcn_global_load_lds( \
    (__attribute__((address_space(1))) u32*)(gp),       \
    (__attribute__((address_space(3))) u32*)(lp), 16, 0, 0)

// ---------------- k_rw: router (cold x) + per-column wamax (cold wgu), fused ----
#define NB_RTR  (T_TOK / 4)  // 2048
#define NB_WAM  (64 * NE)    // 576

__global__ __launch_bounds__(256) void k_rw(
    const float* __restrict__ x, const float* __restrict__ wg,
    const float* __restrict__ wgu, const float* __restrict__ wsg,
    i8* __restrict__ xq, float* __restrict__ sxg,
    int* __restrict__ eidx, float2* __restrict__ wts,
    int* __restrict__ swc_i) {
  const int b = blockIdx.x;
  const int tid = threadIdx.x;

  if (b >= NB_RTR) {
    const int flat = b - NB_RTR;
    const int e = flat >> 6, hb = flat & 63;
    const float* src = (e < 8) ? (wgu + (size_t)e * 1048576) : wsg;
    const int wv = tid >> 6, l = tid & 63;
    float4 m4[4];
#pragma unroll
    for (int j = 0; j < 4; ++j) m4[j] = make_float4(0.f, 0.f, 0.f, 0.f);
    const int r0 = hb * 16 + wv * 4;
#pragma unroll
    for (int r = 0; r < 4; ++r) {
      const float* row = src + (size_t)(r0 + r) * 1024;
#pragma unroll
      for (int j = 0; j < 4; ++j) {
        const float4 v = *(const float4*)&row[j * 256 + l * 4];
        m4[j].x = fmaxf(m4[j].x, fabsf(v.x));
        m4[j].y = fmaxf(m4[j].y, fabsf(v.y));
        m4[j].z = fmaxf(m4[j].z, fabsf(v.z));
        m4[j].w = fmaxf(m4[j].w, fabsf(v.w));
      }
    }
    __shared__ float4 red[4][4][64];
#pragma unroll
    for (int j = 0; j < 4; ++j) red[wv][j][l] = m4[j];
    __syncthreads();
    const int j2 = tid >> 6, l2 = tid & 63;
    const float4 a = red[0][j2][l2], bb = red[1][j2][l2];
    const float4 c = red[2][j2][l2], d = red[3][j2][l2];
    float o[4];
    o[0] = fmaxf(fmaxf(a.x, bb.x), fmaxf(c.x, d.x));
    o[1] = fmaxf(fmaxf(a.y, bb.y), fmaxf(c.y, d.y));
    o[2] = fmaxf(fmaxf(a.z, bb.z), fmaxf(c.z, d.z));
    o[3] = fmaxf(fmaxf(a.w, bb.w), fmaxf(c.w, d.w));
    const int cbase = j2 * 256 + l2 * 4;
#pragma unroll
    for (int k = 0; k < 4; ++k)
      atomicMax(&swc_i[e * 1024 + colp_of(cbase + k)], __float_as_int(o[k]));
    return;
  }

  // ---- router: 4 tokens/block, 1 wave/token; coalesced wg rows ----
  const int t = b * 4 + (tid >> 6);
  const int l = tid & 63;
  float a[8] = {0, 0, 0, 0, 0, 0, 0, 0};
  float vals[16];
  float am = 0.f;
  const float* xr = x + (size_t)t * HID;
#pragma unroll
  for (int j = 0; j < 16; ++j) {
    const int h = j * 64 + l;
    const float xv = xr[h];
    vals[j] = xv;
    am = fmaxf(am, fabsf(xv));
    const float4 w0 = *(const float4*)&wg[h * 8];
    const float4 w1 = *(const float4*)&wg[h * 8 + 4];
    a[0] += xv * w0.x; a[1] += xv * w0.y; a[2] += xv * w0.z; a[3] += xv * w0.w;
    a[4] += xv * w1.x; a[5] += xv * w1.y; a[6] += xv * w1.z; a[7] += xv * w1.w;
  }
#pragma unroll
  for (int off = 32; off >= 1; off >>= 1) {
    am = fmaxf(am, __shfl_xor(am, off));
#pragma unroll
    for (int e2 = 0; e2 < 8; ++e2) a[e2] += __shfl_xor(a[e2], off);
  }
  const float inv = (am > 0.f) ? 127.f / am : 0.f;
  i8* xqr = xq + (size_t)t * HID;
#pragma unroll
  for (int j = 0; j < 16; ++j)
    xqr[j * 64 + l] = (i8)q8(vals[j], inv);
  if (l == 0) {
    sxg[t] = am * (1.f / 127.f);
    int ia = 0;
#pragma unroll
    for (int e2 = 1; e2 < 8; ++e2) if (a[e2] > a[ia]) ia = e2;
    int ib = (ia == 0) ? 1 : 0;
#pragma unroll
    for (int e2 = 0; e2 < 8; ++e2) if (e2 != ia && a[e2] > a[ib]) ib = e2;
    float wa = 1.f / (1.f + expf(a[ib] - a[ia]));
    eidx[t] = ia | (ib << 8);
    wts[t] = make_float2(wa, 1.f - wa);
  }
}

// ---------------- k_prep2: wide-tile weight transposes only ----------------
#define NB_WGUP (128 * NE)   // 1152
#define NB_WDN  (64 * NE)    // 576

__global__ __launch_bounds__(256) void k_prep2(
    const float* __restrict__ wgu, const float* __restrict__ wsg,
    const float* __restrict__ wdn, const float* __restrict__ wsd,
    const int* __restrict__ swc_i,
    i8* __restrict__ wguq, u16* __restrict__ wdT) {
  __shared__ float tile[64][130];
  const int b = blockIdx.x;
  const int tid = threadIdx.x;

  if (b < NB_WGUP) {
    const int e = b / 128, rem = b % 128;
    const int c0 = (rem & 15) * 64, h0 = (rem >> 4) * 128;
    const float* src = (e < 8) ? (wgu + (size_t)e * HID * 1024) : wsg;
    const int hl = tid >> 1, cb = (tid & 1) * 32;
    float4 v[8];
#pragma unroll
    for (int j = 0; j < 8; ++j)
      v[j] = *(const float4*)&src[(size_t)(h0 + hl) * 1024 + c0 + cb + j * 4];
#pragma unroll
    for (int j = 0; j < 8; ++j) {
      tile[cb + j * 4 + 0][hl] = v[j].x;
      tile[cb + j * 4 + 1][hl] = v[j].y;
      tile[cb + j * 4 + 2][hl] = v[j].z;
      tile[cb + j * 4 + 3][hl] = v[j].w;
    }
    __syncthreads();
    const int cl = tid >> 2, hb = (tid & 3) * 32;
    const int cp = colp_of(c0 + cl);
    const float inv = 127.f / __int_as_float(swc_i[e * 1024 + cp]);
    i8 out[32];
#pragma unroll
    for (int k = 0; k < 32; ++k) out[k] = (i8)q8(tile[cl][hb + k], inv);
    i8* dst = &wguq[((size_t)e * 1024 + cp) * 1024 + h0 + hb];
    *(int4*)dst = *(int4*)out;
    *(int4*)(dst + 16) = *(int4*)(out + 16);
    return;
  }
  const int bb = b - NB_WGUP;
  const int e = bb / 64, rem = bb % 64;
  const int h0 = (rem & 15) * 64, i0 = (rem >> 4) * 128;
  const float* src = (e < 8) ? (wdn + (size_t)e * ISZ * HID) : wsd;
  const int il = tid >> 1, hb = (tid & 1) * 32;
  float4 v[8];
#pragma unroll
  for (int j = 0; j < 8; ++j)
    v[j] = *(const float4*)&src[(size_t)(i0 + il) * 1024 + h0 + hb + j * 4];
#pragma unroll
  for (int j = 0; j < 8; ++j) {
    tile[hb + j * 4 + 0][il] = v[j].x;
    tile[hb + j * 4 + 1][il] = v[j].y;
    tile[hb + j * 4 + 2][il] = v[j].z;
    tile[hb + j * 4 + 3][il] = v[j].w;
  }
  __syncthreads();
  const int hl = tid >> 2, ib = (tid & 3) * 32;
  u16 ob[32];
#pragma unroll
  for (int k = 0; k < 32; ++k) ob[k] = f2bf(tile[hl][ib + k]);
  u16* dst = &wdT[((size_t)e * HID + h0 + hl) * ISZ + i0 + ib];
  *(int4*)dst        = *(int4*)ob;
  *(int4*)(dst + 8)  = *(int4*)(ob + 8);
  *(int4*)(dst + 16) = *(int4*)(ob + 16);
  *(int4*)(dst + 24) = *(int4*)(ob + 24);
}

// ---------------- deterministic counting scatter (256-aligned segments) --------
__global__ __launch_bounds__(512) void k_scatter(
    const int* __restrict__ eidx, int* __restrict__ btok, int* __restrict__ slotmap,
    int* __restrict__ seg, int* __restrict__ segcnt) {
  __shared__ int cnt_s[8];
  __shared__ int goff_s[9];
  const int e = threadIdx.x >> 6;
  const int l = threadIdx.x & 63;

  int c1 = 0;
  for (int c = 0; c < T_TOK / 64; ++c) {
    int v = eidx[c * 64 + l];
    c1 += __popcll(__ballot((v & 255) == e)) + __popcll(__ballot(((v >> 8) & 255) == e));
  }
  if (l == 0) cnt_s[e] = c1;
  __syncthreads();
  if (threadIdx.x == 0) {
    int off = 0;
    for (int k = 0; k < 8; ++k) { goff_s[k] = off; off += (cnt_s[k] + 255) & ~255; }
    goff_s[8] = off;
  }
  __syncthreads();
  const int base0 = goff_s[e];
  const int cnt_e = cnt_s[e];
  const unsigned long long below = (l == 63) ? ~0ull >> 1 : ((1ull << l) - 1);

  int base = base0;
  for (int c = 0; c < T_TOK / 64; ++c) {
    const int t = c * 64 + l;
    const int v = eidx[t];
    const unsigned long long ma = __ballot((v & 255) == e);
    const unsigned long long mb = __ballot(((v >> 8) & 255) == e);
    if ((v & 255) == e) {
      int s = base + __popcll(ma & below);
      btok[s] = t; slotmap[2 * t] = s;
    }
    if (((v >> 8) & 255) == e) {
      int s = base + __popcll(ma) + __popcll(mb & below);
      btok[s] = t; slotmap[2 * t + 1] = s;
    }
    base += __popcll(ma) + __popcll(mb);
  }
  for (int p = cnt_e + l; p < ((cnt_e + 255) & ~255); p += 64) btok[base0 + p] = 0;
  if (threadIdx.x < 9) seg[threadIdx.x] = goff_s[threadIdx.x];
  if (threadIdx.x < 8) segcnt[threadIdx.x] = cnt_s[threadIdx.x];
}

__device__ __forceinline__ bool seg_lookup(const int* __restrict__ seg,
                                           const int* __restrict__ segcnt,
                                           int brow, int& e) {
  if (brow >= RBASE) { e = 8; return true; }
  if (brow >= seg[8]) return false;
  e = 0;
#pragma unroll
  for (int k = 1; k < 8; ++k) if (brow >= seg[k]) e = k;
  return brow < seg[e] + segcnt[e];
}

// =================================================================================
// GEMM1 (int8): 256x256 tile, K-slot=64 i8 (64-B rows, 4x16B chunks), 16 slots.
// 8 waves 4M x 2N (per-wave 64x128). LDS: 4-ring A(16KB)+B(16KB) = 128 KB.
// Counted pipeline: stage s+3 during s; vmcnt(12)->8->4->0, never drained
// mid-loop. Chunk swizzle q ^= row&3 both sides. K order identical to r20.
// =================================================================================

#define G1_STG(kt) do { const int _r = ((kt) & 3) * 16384;          \
    STAGE(sA0 + (kt) * 64, Ab + _r + 0 * 8192 + w * 1024);          \
    STAGE(sA1 + (kt) * 64, Ab + _r + 1 * 8192 + w * 1024);          \
    STAGE(sB0 + (kt) * 64, Bb + _r + 0 * 8192 + w * 1024);          \
    STAGE(sB1 + (kt) * 64, Bb + _r + 1 * 8192 + w * 1024); } while (0)

#define G1_LOADF(RG) do {                                           \
    _Pragma("unroll") for (int m = 0; m < 4; ++m)                   \
      fA[m] = *(const i32x4*)&Ab[(RG) * 16384 + aBase + m * 1024];  \
    _Pragma("unroll") for (int n = 0; n < 8; ++n)                   \
      fB[n] = *(const i32x4*)&Bb[(RG) * 16384 + bBase + n * 1024]; } while (0)

#define G1_MFMA do { __builtin_amdgcn_s_setprio(1);                 \
    _Pragma("unroll") for (int m = 0; m < 4; ++m)                   \
      _Pragma("unroll") for (int n = 0; n < 8; ++n)                 \
        acc[m][n] = __builtin_amdgcn_mfma_i32_16x16x64_i8(fA[m], fB[n], acc[m][n], 0, 0, 0); \
    __builtin_amdgcn_s_setprio(0); } while (0)

__global__ __launch_bounds__(512) void k_gemm_gu(
    const i8* __restrict__ xq, const i8* __restrict__ wguq,
    const int* __restrict__ seg, const int* __restrict__ segcnt,
    const int* __restrict__ btok, const float* __restrict__ sxg,
    const int* __restrict__ swc_i,
    u16* __restrict__ act)
{
  const int bid = blockIdx.x;
  const int brow = (bid % NROWB) * BM;
  const int bcol = (bid / NROWB) * 256;
  int e;
  if (!seg_lookup(seg, segcnt, brow, e)) return;

  __shared__ __align__(16) i8 Ab[4 * 16384];   // 64 KB
  __shared__ __align__(16) i8 Bb[4 * 16384];   // 64 KB
  __shared__ float sxl[BM];
  __shared__ float swcl[256];

  const int tid = threadIdx.x;
  const int w = tid >> 6, l = tid & 63;
  const int wm = w >> 1, wn = w & 1;           // 4M x 2N -> 64x128 per wave
  const int fr = l & 15, fg = l >> 4;

  if (tid < BM) {
    const int rrow = brow + tid;
    const int tk = (e < 8) ? btok[rrow] : (rrow - RBASE);
    sxl[tid] = sxg[tk];
  } else {
    swcl[tid - 256] = __int_as_float(swc_i[e * 1024 + bcol + (tid - 256)]) * (1.f / 127.f);
  }

  // staging: instr j covers rows j*128 + w*16 + (l>>2), 16B chunk (l&3),
  // pre-swizzled source chunk = (l&3) ^ ((l>>2)&3)
  const int rr = w * 16 + (l >> 2);            // row within 128-row half
  const int sw = ((l & 3) ^ ((l >> 2) & 3)) * 16;
  int tr[2];
#pragma unroll
  for (int j = 0; j < 2; ++j) {
    const int gr = brow + j * 128 + rr;
    tr[j] = (e < 8) ? btok[gr] : (gr - RBASE);
  }
  const i8* sA0 = xq + (size_t)tr[0] * HID + sw;
  const i8* sA1 = xq + (size_t)tr[1] * HID + sw;
  const i8* sB0 = wguq + ((size_t)e * 1024 + bcol + 0 * 128 + rr) * HID + sw;
  const i8* sB1 = wguq + ((size_t)e * 1024 + bcol + 1 * 128 + rr) * HID + sw;

  // read geometry: row*64 bytes + swizzled 16B chunk
  const int aBase = (wm * 64 + fr) * 64 + ((fg ^ (fr & 3)) * 16);
  const int bBase = (wn * 128 + fr) * 64 + ((fg ^ (fr & 3)) * 16);

  i32x4 acc[4][8];
#pragma unroll
  for (int m = 0; m < 4; ++m)
#pragma unroll
    for (int n = 0; n < 8; ++n) acc[m][n] = (i32x4){0, 0, 0, 0};
  i32x4 fA[4], fB[8];

  const int NKT = HID / 64;   // 16 slots
  G1_STG(0); G1_STG(1); G1_STG(2);
  for (int s = 0; s < NKT; ++s) {
    if (s + 3 < NKT) G1_STG(s + 3);
    if (s <= NKT - 4)      { asm volatile("s_waitcnt vmcnt(12)" ::: "memory"); }
    else if (s == NKT - 3) { asm volatile("s_waitcnt vmcnt(8)"  ::: "memory"); }
    else if (s == NKT - 2) { asm volatile("s_waitcnt vmcnt(4)"  ::: "memory"); }
    else                   { asm volatile("s_waitcnt vmcnt(0)"  ::: "memory"); }
    __builtin_amdgcn_s_barrier();
    G1_LOADF(s & 3);
    asm volatile("s_waitcnt lgkmcnt(0)" ::: "memory");
    __builtin_amdgcn_sched_barrier(0);
    G1_MFMA;
    __builtin_amdgcn_s_barrier();
  }

#pragma unroll
  for (int m = 0; m < 4; ++m) {
#pragma unroll
    for (int p = 0; p < 4; ++p) {
      const i32x4 gI = acc[m][2 * p], uI = acc[m][2 * p + 1];
      const int col = ((bcol + wn * 128) >> 1) + p * 16 + fr;
      const float swg = swcl[wn * 128 + p * 32 + fr];
      const float swu = swcl[wn * 128 + p * 32 + 16 + fr];
#pragma unroll
      for (int r = 0; r < 4; ++r) {
        const int row_l = wm * 64 + m * 16 + fg * 4 + r;
        const float sx = sxl[row_l];
        const float gate = (float)gI[r] * (sx * swg);
        const float up   = (float)uI[r] * (sx * swu);
        const float sv = gate / (1.f + __expf(-gate));
        act[(size_t)(brow + row_l) * ISZ + col] = f2bf(sv * up);
      }
    }
  }
}

// =================================================================================
// GEMM2 (bf16): mirror. K-slot=32 bf16 (64-B rows), 16 slots, 4-ring 128 KB,
// counted vmcnt(12)->8->4->0, q ^= row&3 swizzle. K order identical to r20.
// =================================================================================

#define G2_STG(kt) do { const int _r = ((kt) & 3) * 8192;           \
    STAGE(dA0 + (kt) * 32, As2 + _r + 0 * 4096 + w * 512);          \
    STAGE(dA1 + (kt) * 32, As2 + _r + 1 * 4096 + w * 512);          \
    STAGE(dB0 + (kt) * 32, Bs2 + _r + 0 * 4096 + w * 512);          \
    STAGE(dB1 + (kt) * 32, Bs2 + _r + 1 * 4096 + w * 512); } while (0)

#define G2_LOADF(RG) do {                                           \
    _Pragma("unroll") for (int m = 0; m < 4; ++m)                   \
      gA[m] = *(const short8*)&As2[(RG) * 8192 + aBase + m * 512];  \
    _Pragma("unroll") for (int n = 0; n < 8; ++n)                   \
      gB[n] = *(const short8*)&Bs2[(RG) * 8192 + bBase + n * 512]; } while (0)

#define G2_MFMA do { __builtin_amdgcn_s_setprio(1);                 \
    _Pragma("unroll") for (int m = 0; m < 4; ++m)                   \
      _Pragma("unroll") for (int n = 0; n < 8; ++n)                 \
        accf[m][n] = __builtin_amdgcn_mfma_f32_16x16x32_bf16(gA[m], gB[n], accf[m][n], 0, 0, 0); \
    __builtin_amdgcn_s_setprio(0); } while (0)

__global__ __launch_bounds__(512) void k_gemm_down(
    const u16* __restrict__ act, const u16* __restrict__ wdT,
    const int* __restrict__ seg, const int* __restrict__ segcnt,
    u16* __restrict__ tmp) {
  const int bid = blockIdx.x;
  const int brow = (bid % NROWB) * BM;
  const int bcol = (bid / NROWB) * 256;
  int e;
  if (!seg_lookup(seg, segcnt, brow, e)) return;

  __shared__ __align__(16) u16 As2[4 * 8192];   // 64 KB
  __shared__ __align__(16) u16 Bs2[4 * 8192];   // 64 KB

  const int tid = threadIdx.x;
  const int w = tid >> 6, l = tid & 63;
  const int wm = w >> 1, wn = w & 1;            // 4M x 2N -> 64x128 per wave
  const int fr = l & 15, fg = l >> 4;

  const int rr = w * 16 + (l >> 2);
  const int sw = ((l & 3) ^ ((l >> 2) & 3)) * 8;   // 16B chunk in bf16 elems
  const u16* dA0 = act + (size_t)(brow + 0 * 128 + rr) * ISZ + sw;
  const u16* dA1 = act + (size_t)(brow + 1 * 128 + rr) * ISZ + sw;
  const u16* dB0 = wdT + ((size_t)e * 1024 + bcol + 0 * 128 + rr) * ISZ + sw;
  const u16* dB1 = wdT + ((size_t)e * 1024 + bcol + 1 * 128 + rr) * ISZ + sw;

  const int aBase = (wm * 64 + fr) * 32 + ((fg ^ (fr & 3)) * 8);
  const int bBase = (wn * 128 + fr) * 32 + ((fg ^ (fr & 3)) * 8);

  f32x4 accf[4][8];
#pragma unroll
  for (int m = 0; m < 4; ++m)
#pragma unroll
    for (int n = 0; n < 8; ++n) accf[m][n] = (f32x4){0.f, 0.f, 0.f, 0.f};
  short8 gA[4], gB[8];

  const int NKT = ISZ / 32;   // 16 slots
  G2_STG(0); G2_STG(1); G2_STG(2);
  for (int s = 0; s < NKT; ++s) {
    if (s + 3 < NKT) G2_STG(s + 3);
    if (s <= NKT - 4)      { asm volatile("s_waitcnt vmcnt(12)" ::: "memory"); }
    else if (s == NKT - 3) { asm volatile("s_waitcnt vmcnt(8)"  ::: "memory"); }
    else if (s == NKT - 2) { asm volatile("s_waitcnt vmcnt(4)"  ::: "memory"); }
    else                   { asm volatile("s_waitcnt vmcnt(0)"  ::: "memory"); }
    __builtin_amdgcn_s_barrier();
    G2_LOADF(s & 3);
    asm volatile("s_waitcnt lgkmcnt(0)" ::: "memory");
    __builtin_amdgcn_sched_barrier(0);
    G2_MFMA;
    __builtin_amdgcn_s_barrier();
  }

#pragma unroll
  for (int m = 0; m < 4; ++m) {
#pragma unroll
    for (int r = 0; r < 4; ++r) {
      const int row = brow + wm * 64 + m * 16 + fg * 4 + r;
#pragma unroll
      for (int n = 0; n < 8; ++n) {
        const int col = bcol + wn * 128 + n * 16 + fr;
        tmp[(size_t)row * HID + col] = f2bf(accf[m][n][r]);
      }
    }
  }
}

// ---------------- combine: out[t] = tmp[sh] + w0*tmp[s0] + w1*tmp[s1] -----------
__global__ __launch_bounds__(256) void k_combine(
    const u16* __restrict__ tmp, const int* __restrict__ slotmap,
    const float2* __restrict__ wts, float* __restrict__ out) {
  const int idx = blockIdx.x * 256 + threadIdx.x;
  const int t = idx >> 7;
  const int c = (idx & 127) << 3;
  const int s0 = slotmap[2 * t], s1 = slotmap[2 * t + 1];
  const float2 wv = wts[t];
  const short8 a = *(const short8*)(tmp + (size_t)s0 * HID + c);
  const short8 b = *(const short8*)(tmp + (size_t)s1 * HID + c);
  const short8 s = *(const short8*)(tmp + (size_t)(RBASE + t) * HID + c);
  float r[8];
#pragma unroll
  for (int j = 0; j < 8; ++j)
    r[j] = bf2f((u16)s[j]) + wv.x * bf2f((u16)a[j]) + wv.y * bf2f((u16)b[j]);
  float* po = out + (size_t)t * HID + c;
  *(float4*)po       = make_float4(r[0], r[1], r[2], r[3]);
  *(float4*)(po + 4) = make_float4(r[4], r[5], r[6], r[7]);
}

// ---------------- launch ----------------
extern "C" void kernel_launch(void* const* d_in, const int* in_sizes, int n_in,
                              void* d_out, int out_size, void* d_ws, size_t ws_size,
                              hipStream_t stream) {
  const float* x   = (const float*)d_in[0];
  const float* wg  = (const float*)d_in[1];
  const float* wgu = (const float*)d_in[2];
  const float* wdn = (const float*)d_in[3];
  const float* wsg = (const float*)d_in[4];
  const float* wsd = (const float*)d_in[5];
  float* out = (float*)d_out;

  char* ws = (char*)d_ws;
  i8*  xq    = (i8*)ws;   ws += (size_t)T_TOK * HID;
  i8*  wguq  = (i8*)ws;   ws += (size_t)NE * 1024 * HID;
  u16* wdT   = (u16*)ws;  ws += (size_t)NE * HID * ISZ * 2;
  u16* actb  = (u16*)ws;  ws += (size_t)NSLOT * ISZ * 2;
  u16* tmp   = (u16*)ws;  ws += (size_t)NSLOT * HID * 2;
  float* sxg = (float*)ws; ws += (size_t)T_TOK * 4;
  int* swc_i = (int*)ws;  ws += (size_t)NE * 1024 * 4;
  int* eidx  = (int*)ws;  ws += (size_t)T_TOK * 4;
  float2* wt = (float2*)ws; ws += (size_t)T_TOK * 8;
  int* btok  = (int*)ws;  ws += (size_t)RBASE * 4;
  int* smap  = (int*)ws;  ws += (size_t)2 * T_TOK * 4;
  int* seg   = (int*)ws;  ws += 16 * 4;
  int* segc  = (int*)ws;

  k_rw<<<NB_RTR + NB_WAM, 256, 0, stream>>>(
      x, wg, wgu, wsg, xq, sxg, eidx, wt, swc_i);
  k_prep2<<<NB_WGUP + NB_WDN, 256, 0, stream>>>(
      wgu, wsg, wdn, wsd, swc_i, wguq, wdT);
  k_scatter<<<1, 512, 0, stream>>>(eidx, btok, smap, seg, segc);
  k_gemm_gu<<<NROWB * 4, 512, 0, stream>>>(
      xq, wguq, seg, segc, btok, sxg, swc_i, actb);
  k_gemm_down<<<NROWB * 4, 512, 0, stream>>>(actb, wdT, seg, segc, tmp);
  k_combine<<<(T_TOK * HID / 8) / 256, 256, 0, stream>>>(tmp, smap, wt, out);
}

// Round 22
// 180.562 us; speedup vs baseline: 1.1272x; 1.1272x over previous
//
#include <hip/hip_runtime.h>
#include <hip/hip_bf16.h>
#include <cstdint>

#define T_TOK 8192
#define HID   1024
#define NE    9
#define ISZ   512
#define RBASE 18432
#define NSLOT (RBASE + T_TOK)   // 26624

#define BM 256
#define NROWB (NSLOT / BM)      // 104

typedef unsigned short u16;
typedef unsigned int   u32;
typedef signed char    i8;
typedef __attribute__((ext_vector_type(8))) short short8;
typedef __attribute__((ext_vector_type(4))) float f32x4;
typedef __attribute__((ext_vector_type(4))) int   i32x4;

__device__ __forceinline__ u16 f2bf(float f) {
  u32 u = __builtin_bit_cast(u32, f);
  return (u16)((u + 0x7fffu + ((u >> 16) & 1u)) >> 16);
}
__device__ __forceinline__ float bf2f(u16 v) {
  return __builtin_bit_cast(float, (u32)v << 16);
}
__device__ __forceinline__ int q8(float v, float inv) {
  int q = (int)__builtin_rintf(v * inv);
  return (q > 127) ? 127 : ((q < -127) ? -127 : q);
}
__device__ __forceinline__ int colp_of(int c) {
  int i = (c < 512) ? c : (c - 512);
  return (i >> 4) * 32 + ((c < 512) ? 0 : 16) + (i & 15);
}

#define STAGE(gp, lp) __builtin_amdgcn_global_load_lds( \
    (__attribute__((address_space(1))) u32*)(gp),       \
    (__attribute__((address_space(3))) u32*)(lp), 16, 0, 0)

// ---------------- k_rw: router (cold x) + per-column wamax (cold wgu), fused ----
#define NB_RTR  (T_TOK / 4)  // 2048
#define NB_WAM  (64 * NE)    // 576

__global__ __launch_bounds__(256) void k_rw(
    const float* __restrict__ x, const float* __restrict__ wg,
    const float* __restrict__ wgu, const float* __restrict__ wsg,
    i8* __restrict__ xq, float* __restrict__ sxg,
    int* __restrict__ eidx, float2* __restrict__ wts,
    int* __restrict__ swc_i) {
  const int b = blockIdx.x;
  const int tid = threadIdx.x;

  if (b >= NB_RTR) {
    // ---- wamax: block = 16 rows x 1024 cols of expert e; atomicMax (det.) ----
    const int flat = b - NB_RTR;
    const int e = flat >> 6, hb = flat & 63;
    const float* src = (e < 8) ? (wgu + (size_t)e * 1048576) : wsg;
    const int wv = tid >> 6, l = tid & 63;
    float4 m4[4];
#pragma unroll
    for (int j = 0; j < 4; ++j) m4[j] = make_float4(0.f, 0.f, 0.f, 0.f);
    const int r0 = hb * 16 + wv * 4;
#pragma unroll
    for (int r = 0; r < 4; ++r) {
      const float* row = src + (size_t)(r0 + r) * 1024;
#pragma unroll
      for (int j = 0; j < 4; ++j) {
        const float4 v = *(const float4*)&row[j * 256 + l * 4];
        m4[j].x = fmaxf(m4[j].x, fabsf(v.x));
        m4[j].y = fmaxf(m4[j].y, fabsf(v.y));
        m4[j].z = fmaxf(m4[j].z, fabsf(v.z));
        m4[j].w = fmaxf(m4[j].w, fabsf(v.w));
      }
    }
    __shared__ float4 red[4][4][64];
#pragma unroll
    for (int j = 0; j < 4; ++j) red[wv][j][l] = m4[j];
    __syncthreads();
    const int j2 = tid >> 6, l2 = tid & 63;
    const float4 a = red[0][j2][l2], bb = red[1][j2][l2];
    const float4 c = red[2][j2][l2], d = red[3][j2][l2];
    float o[4];
    o[0] = fmaxf(fmaxf(a.x, bb.x), fmaxf(c.x, d.x));
    o[1] = fmaxf(fmaxf(a.y, bb.y), fmaxf(c.y, d.y));
    o[2] = fmaxf(fmaxf(a.z, bb.z), fmaxf(c.z, d.z));
    o[3] = fmaxf(fmaxf(a.w, bb.w), fmaxf(c.w, d.w));
    const int cbase = j2 * 256 + l2 * 4;
#pragma unroll
    for (int k = 0; k < 4; ++k)
      atomicMax(&swc_i[e * 1024 + colp_of(cbase + k)], __float_as_int(o[k]));
    return;
  }

  // ---- router: 4 tokens/block, 1 wave/token; COALESCED wg rows (h = j*64+l) ----
  const int t = b * 4 + (tid >> 6);
  const int l = tid & 63;
  float a[8] = {0, 0, 0, 0, 0, 0, 0, 0};
  float vals[16];
  float am = 0.f;
  const float* xr = x + (size_t)t * HID;
#pragma unroll
  for (int j = 0; j < 16; ++j) {
    const int h = j * 64 + l;
    const float xv = xr[h];                       // 256B/wave coalesced
    vals[j] = xv;
    am = fmaxf(am, fabsf(xv));
    const float4 w0 = *(const float4*)&wg[h * 8]; // 32B/lane contiguous rows
    const float4 w1 = *(const float4*)&wg[h * 8 + 4];
    a[0] += xv * w0.x; a[1] += xv * w0.y; a[2] += xv * w0.z; a[3] += xv * w0.w;
    a[4] += xv * w1.x; a[5] += xv * w1.y; a[6] += xv * w1.z; a[7] += xv * w1.w;
  }
#pragma unroll
  for (int off = 32; off >= 1; off >>= 1) {
    am = fmaxf(am, __shfl_xor(am, off));
#pragma unroll
    for (int e2 = 0; e2 < 8; ++e2) a[e2] += __shfl_xor(a[e2], off);
  }
  const float inv = (am > 0.f) ? 127.f / am : 0.f;
  i8* xqr = xq + (size_t)t * HID;
#pragma unroll
  for (int j = 0; j < 16; ++j)
    xqr[j * 64 + l] = (i8)q8(vals[j], inv);       // 64B/wave coalesced
  if (l == 0) {
    sxg[t] = am * (1.f / 127.f);
    int ia = 0;
#pragma unroll
    for (int e2 = 1; e2 < 8; ++e2) if (a[e2] > a[ia]) ia = e2;
    int ib = (ia == 0) ? 1 : 0;
#pragma unroll
    for (int e2 = 0; e2 < 8; ++e2) if (e2 != ia && a[e2] > a[ib]) ib = e2;
    float wa = 1.f / (1.f + expf(a[ib] - a[ia]));
    eidx[t] = ia | (ib << 8);
    wts[t] = make_float2(wa, 1.f - wa);
  }
}

// ---------------- k_prep2: wide-tile weight transposes only ----------------
#define NB_WGUP (128 * NE)   // 1152
#define NB_WDN  (64 * NE)    // 576

__global__ __launch_bounds__(256) void k_prep2(
    const float* __restrict__ wgu, const float* __restrict__ wsg,
    const float* __restrict__ wdn, const float* __restrict__ wsd,
    const int* __restrict__ swc_i,
    i8* __restrict__ wguq, u16* __restrict__ wdT) {
  __shared__ float tile[64][130];
  const int b = blockIdx.x;
  const int tid = threadIdx.x;

  if (b < NB_WGUP) {
    const int e = b / 128, rem = b % 128;
    const int c0 = (rem & 15) * 64, h0 = (rem >> 4) * 128;
    const float* src = (e < 8) ? (wgu + (size_t)e * HID * 1024) : wsg;
    const int hl = tid >> 1, cb = (tid & 1) * 32;
    float4 v[8];
#pragma unroll
    for (int j = 0; j < 8; ++j)
      v[j] = *(const float4*)&src[(size_t)(h0 + hl) * 1024 + c0 + cb + j * 4];
#pragma unroll
    for (int j = 0; j < 8; ++j) {
      tile[cb + j * 4 + 0][hl] = v[j].x;
      tile[cb + j * 4 + 1][hl] = v[j].y;
      tile[cb + j * 4 + 2][hl] = v[j].z;
      tile[cb + j * 4 + 3][hl] = v[j].w;
    }
    __syncthreads();
    const int cl = tid >> 2, hb = (tid & 3) * 32;
    const int cp = colp_of(c0 + cl);
    const float inv = 127.f / __int_as_float(swc_i[e * 1024 + cp]);
    i8 out[32];
#pragma unroll
    for (int k = 0; k < 32; ++k) out[k] = (i8)q8(tile[cl][hb + k], inv);
    i8* dst = &wguq[((size_t)e * 1024 + cp) * 1024 + h0 + hb];
    *(int4*)dst = *(int4*)out;
    *(int4*)(dst + 16) = *(int4*)(out + 16);
    return;
  }
  const int bb = b - NB_WGUP;
  const int e = bb / 64, rem = bb % 64;
  const int h0 = (rem & 15) * 64, i0 = (rem >> 4) * 128;
  const float* src = (e < 8) ? (wdn + (size_t)e * ISZ * HID) : wsd;
  const int il = tid >> 1, hb = (tid & 1) * 32;
  float4 v[8];
#pragma unroll
  for (int j = 0; j < 8; ++j)
    v[j] = *(const float4*)&src[(size_t)(i0 + il) * 1024 + h0 + hb + j * 4];
#pragma unroll
  for (int j = 0; j < 8; ++j) {
    tile[hb + j * 4 + 0][il] = v[j].x;
    tile[hb + j * 4 + 1][il] = v[j].y;
    tile[hb + j * 4 + 2][il] = v[j].z;
    tile[hb + j * 4 + 3][il] = v[j].w;
  }
  __syncthreads();
  const int hl = tid >> 2, ib = (tid & 3) * 32;
  u16 ob[32];
#pragma unroll
  for (int k = 0; k < 32; ++k) ob[k] = f2bf(tile[hl][ib + k]);
  u16* dst = &wdT[((size_t)e * HID + h0 + hl) * ISZ + i0 + ib];
  *(int4*)dst        = *(int4*)ob;
  *(int4*)(dst + 8)  = *(int4*)(ob + 8);
  *(int4*)(dst + 16) = *(int4*)(ob + 16);
  *(int4*)(dst + 24) = *(int4*)(ob + 24);
}

// ---------------- deterministic counting scatter (256-aligned segments) --------
__global__ __launch_bounds__(512) void k_scatter(
    const int* __restrict__ eidx, int* __restrict__ btok, int* __restrict__ slotmap,
    int* __restrict__ seg, int* __restrict__ segcnt) {
  __shared__ int cnt_s[8];
  __shared__ int goff_s[9];
  const int e = threadIdx.x >> 6;
  const int l = threadIdx.x & 63;

  int c1 = 0;
  for (int c = 0; c < T_TOK / 64; ++c) {
    int v = eidx[c * 64 + l];
    c1 += __popcll(__ballot((v & 255) == e)) + __popcll(__ballot(((v >> 8) & 255) == e));
  }
  if (l == 0) cnt_s[e] = c1;
  __syncthreads();
  if (threadIdx.x == 0) {
    int off = 0;
    for (int k = 0; k < 8; ++k) { goff_s[k] = off; off += (cnt_s[k] + 255) & ~255; }
    goff_s[8] = off;
  }
  __syncthreads();
  const int base0 = goff_s[e];
  const int cnt_e = cnt_s[e];
  const unsigned long long below = (l == 63) ? ~0ull >> 1 : ((1ull << l) - 1);

  int base = base0;
  for (int c = 0; c < T_TOK / 64; ++c) {
    const int t = c * 64 + l;
    const int v = eidx[t];
    const unsigned long long ma = __ballot((v & 255) == e);
    const unsigned long long mb = __ballot(((v >> 8) & 255) == e);
    if ((v & 255) == e) {
      int s = base + __popcll(ma & below);
      btok[s] = t; slotmap[2 * t] = s;
    }
    if (((v >> 8) & 255) == e) {
      int s = base + __popcll(ma) + __popcll(mb & below);
      btok[s] = t; slotmap[2 * t + 1] = s;
    }
    base += __popcll(ma) + __popcll(mb);
  }
  for (int p = cnt_e + l; p < ((cnt_e + 255) & ~255); p += 64) btok[base0 + p] = 0;
  if (threadIdx.x < 9) seg[threadIdx.x] = goff_s[threadIdx.x];
  if (threadIdx.x < 8) segcnt[threadIdx.x] = cnt_s[threadIdx.x];
}

__device__ __forceinline__ bool seg_lookup(const int* __restrict__ seg,
                                           const int* __restrict__ segcnt,
                                           int brow, int& e) {
  if (brow >= RBASE) { e = 8; return true; }
  if (brow >= seg[8]) return false;
  e = 0;
#pragma unroll
  for (int k = 1; k < 8; ++k) if (brow >= seg[k]) e = k;
  return brow < seg[e] + segcnt[e];
}

// =================================================================================
// GEMM1 (int8): 256x256 tile, K-slot=128 i8, 8 waves 4M x 2N (per-wave 64x128).
// LDS: 2-ring A + 2-ring B = 128KB. Depth-1 stage-ahead, ^(row&7) swizzle.
// =================================================================================

#define G1_STG(kt) do { const int _r = ((kt) & 1) * 32768;          \
    STAGE(sA0 + (kt) * 128, Ab + _r + 0 * 8192 + w * 1024);         \
    STAGE(sA1 + (kt) * 128, Ab + _r + 1 * 8192 + w * 1024);         \
    STAGE(sA2 + (kt) * 128, Ab + _r + 2 * 8192 + w * 1024);         \
    STAGE(sA3 + (kt) * 128, Ab + _r + 3 * 8192 + w * 1024);         \
    STAGE(sB0 + (kt) * 128, Bb + _r + 0 * 8192 + w * 1024);         \
    STAGE(sB1 + (kt) * 128, Bb + _r + 1 * 8192 + w * 1024);         \
    STAGE(sB2 + (kt) * 128, Bb + _r + 2 * 8192 + w * 1024);         \
    STAGE(sB3 + (kt) * 128, Bb + _r + 3 * 8192 + w * 1024); } while (0)

#define G1_LOADF(RG, KX) do {                                       \
    _Pragma("unroll") for (int m = 0; m < 4; ++m)                   \
      fA[m] = *(const i32x4*)&Ab[(RG) * 32768 + aBase + m * 2048 + (KX)]; \
    _Pragma("unroll") for (int n = 0; n < 8; ++n)                   \
      fB[n] = *(const i32x4*)&Bb[(RG) * 32768 + bBase + n * 2048 + (KX)]; } while (0)

#define G1_MFMA do { __builtin_amdgcn_s_setprio(1);                 \
    _Pragma("unroll") for (int m = 0; m < 4; ++m)                   \
      _Pragma("unroll") for (int n = 0; n < 8; ++n)                 \
        acc[m][n] = __builtin_amdgcn_mfma_i32_16x16x64_i8(fA[m], fB[n], acc[m][n], 0, 0, 0); \
    __builtin_amdgcn_s_setprio(0); } while (0)

__global__ __launch_bounds__(512) void k_gemm_gu(
    const i8* __restrict__ xq, const i8* __restrict__ wguq,
    const int* __restrict__ seg, const int* __restrict__ segcnt,
    const int* __restrict__ btok, const float* __restrict__ sxg,
    const int* __restrict__ swc_i,
    u16* __restrict__ act)
{
  const int bid = blockIdx.x;
  const int brow = (bid % NROWB) * BM;
  const int bcol = (bid / NROWB) * 256;
  int e;
  if (!seg_lookup(seg, segcnt, brow, e)) return;

  __shared__ __align__(16) i8 Ab[2 * 32768];
  __shared__ __align__(16) i8 Bb[2 * 32768];
  __shared__ float sxl[BM];
  __shared__ float swcl[256];

  const int tid = threadIdx.x;
  const int w = tid >> 6, l = tid & 63;
  const int wm = w >> 1, wn = w & 1;
  const int fr = l & 15, fg = l >> 4;

  if (tid < BM) {
    const int rrow = brow + tid;
    const int tk = (e < 8) ? btok[rrow] : (rrow - RBASE);
    sxl[tid] = sxg[tk];
  } else {
    swcl[tid - 256] = __int_as_float(swc_i[e * 1024 + bcol + (tid - 256)]) * (1.f / 127.f);
  }

  const int rr = w * 8 + (l >> 3);
  const int sw = ((l & 7) ^ (l >> 3)) * 16;
  int tr[4];
#pragma unroll
  for (int j = 0; j < 4; ++j) {
    const int gr = brow + j * 64 + rr;
    tr[j] = (e < 8) ? btok[gr] : (gr - RBASE);
  }
  const i8* sA0 = xq + (size_t)tr[0] * HID + sw;
  const i8* sA1 = xq + (size_t)tr[1] * HID + sw;
  const i8* sA2 = xq + (size_t)tr[2] * HID + sw;
  const i8* sA3 = xq + (size_t)tr[3] * HID + sw;
  const i8* sB0 = wguq + ((size_t)e * 1024 + bcol + 0 * 64 + rr) * HID + sw;
  const i8* sB1 = wguq + ((size_t)e * 1024 + bcol + 1 * 64 + rr) * HID + sw;
  const i8* sB2 = wguq + ((size_t)e * 1024 + bcol + 2 * 64 + rr) * HID + sw;
  const i8* sB3 = wguq + ((size_t)e * 1024 + bcol + 3 * 64 + rr) * HID + sw;

  const int aBase = (wm * 64 + fr) * 128;
  const int bBase = (wn * 128 + fr) * 128;
  const int kx0 = (fg ^ (fr & 7)) * 16;
  const int kx1 = kx0 ^ 64;

  i32x4 acc[4][8];
#pragma unroll
  for (int m = 0; m < 4; ++m)
#pragma unroll
    for (int n = 0; n < 8; ++n) acc[m][n] = (i32x4){0, 0, 0, 0};
  i32x4 fA[4], fB[8];

  const int NKT = HID / 128;
  G1_STG(0);
  asm volatile("s_waitcnt vmcnt(0)" ::: "memory");
  __builtin_amdgcn_s_barrier();
  for (int s = 0; s < NKT; ++s) {
    const int rg = s & 1;
    if (s + 1 < NKT) G1_STG(s + 1);
    G1_LOADF(rg, kx0);
    asm volatile("s_waitcnt lgkmcnt(0)" ::: "memory");
    __builtin_amdgcn_sched_barrier(0);
    G1_MFMA;
    G1_LOADF(rg, kx1);
    asm volatile("s_waitcnt lgkmcnt(0)" ::: "memory");
    __builtin_amdgcn_sched_barrier(0);
    G1_MFMA;
    asm volatile("s_waitcnt vmcnt(0)" ::: "memory");
    __builtin_amdgcn_s_barrier();
  }

#pragma unroll
  for (int m = 0; m < 4; ++m) {
#pragma unroll
    for (int p = 0; p < 4; ++p) {
      const i32x4 gI = acc[m][2 * p], uI = acc[m][2 * p + 1];
      const int col = ((bcol + wn * 128) >> 1) + p * 16 + fr;
      const float swg = swcl[wn * 128 + p * 32 + fr];
      const float swu = swcl[wn * 128 + p * 32 + 16 + fr];
#pragma unroll
      for (int r = 0; r < 4; ++r) {
        const int row_l = wm * 64 + m * 16 + fg * 4 + r;
        const float sx = sxl[row_l];
        const float gate = (float)gI[r] * (sx * swg);
        const float up   = (float)uI[r] * (sx * swu);
        const float sv = gate / (1.f + __expf(-gate));
        act[(size_t)(brow + row_l) * ISZ + col] = f2bf(sv * up);
      }
    }
  }
}

// =================================================================================
// GEMM2 (bf16): mirror of GEMM1. K-slot=64 bf16, 2-ring LDS, ^(row&7) swizzle.
// =================================================================================

#define G2_STG(kt) do { const int _r = ((kt) & 1) * 16384;          \
    STAGE(dA0 + (kt) * 64, As2 + _r + 0 * 4096 + w * 512);          \
    STAGE(dA1 + (kt) * 64, As2 + _r + 1 * 4096 + w * 512);          \
    STAGE(dA2 + (kt) * 64, As2 + _r + 2 * 4096 + w * 512);          \
    STAGE(dA3 + (kt) * 64, As2 + _r + 3 * 4096 + w * 512);          \
    STAGE(dB0 + (kt) * 64, Bs2 + _r + 0 * 4096 + w * 512);          \
    STAGE(dB1 + (kt) * 64, Bs2 + _r + 1 * 4096 + w * 512);          \
    STAGE(dB2 + (kt) * 64, Bs2 + _r + 2 * 4096 + w * 512);          \
    STAGE(dB3 + (kt) * 64, Bs2 + _r + 3 * 4096 + w * 512); } while (0)

#define G2_LOADF(RG, KX) do {                                       \
    _Pragma("unroll") for (int m = 0; m < 4; ++m)                   \
      gA[m] = *(const short8*)&As2[(RG) * 16384 + aBase + m * 1024 + (KX)]; \
    _Pragma("unroll") for (int n = 0; n < 8; ++n)                   \
      gB[n] = *(const short8*)&Bs2[(RG) * 16384 + bBase + n * 1024 + (KX)]; } while (0)

#define G2_MFMA do { __builtin_amdgcn_s_setprio(1);                 \
    _Pragma("unroll") for (int m = 0; m < 4; ++m)                   \
      _Pragma("unroll") for (int n = 0; n < 8; ++n)                 \
        accf[m][n] = __builtin_amdgcn_mfma_f32_16x16x32_bf16(gA[m], gB[n], accf[m][n], 0, 0, 0); \
    __builtin_amdgcn_s_setprio(0); } while (0)

__global__ __launch_bounds__(512) void k_gemm_down(
    const u16* __restrict__ act, const u16* __restrict__ wdT,
    const int* __restrict__ seg, const int* __restrict__ segcnt,
    u16* __restrict__ tmp) {
  const int bid = blockIdx.x;
  const int brow = (bid % NROWB) * BM;
  const int bcol = (bid / NROWB) * 256;
  int e;
  if (!seg_lookup(seg, segcnt, brow, e)) return;

  __shared__ __align__(16) u16 As2[2 * 16384];
  __shared__ __align__(16) u16 Bs2[2 * 16384];

  const int tid = threadIdx.x;
  const int w = tid >> 6, l = tid & 63;
  const int wm = w >> 1, wn = w & 1;
  const int fr = l & 15, fg = l >> 4;

  const int rr = w * 8 + (l >> 3);
  const int sw = ((l & 7) ^ (l >> 3)) * 8;
  const u16* dA0 = act + (size_t)(brow + 0 * 64 + rr) * ISZ + sw;
  const u16* dA1 = act + (size_t)(brow + 1 * 64 + rr) * ISZ + sw;
  const u16* dA2 = act + (size_t)(brow + 2 * 64 + rr) * ISZ + sw;
  const u16* dA3 = act + (size_t)(brow + 3 * 64 + rr) * ISZ + sw;
  const u16* dB0 = wdT + ((size_t)e * 1024 + bcol + 0 * 64 + rr) * ISZ + sw;
  const u16* dB1 = wdT + ((size_t)e * 1024 + bcol + 1 * 64 + rr) * ISZ + sw;
  const u16* dB2 = wdT + ((size_t)e * 1024 + bcol + 2 * 64 + rr) * ISZ + sw;
  const u16* dB3 = wdT + ((size_t)e * 1024 + bcol + 3 * 64 + rr) * ISZ + sw;

  const int aBase = (wm * 64 + fr) * 64;
  const int bBase = (wn * 128 + fr) * 64;
  const int kx0 = (fg ^ (fr & 7)) * 8;
  const int kx1 = kx0 ^ 32;

  f32x4 accf[4][8];
#pragma unroll
  for (int m = 0; m < 4; ++m)
#pragma unroll
    for (int n = 0; n < 8; ++n) accf[m][n] = (f32x4){0.f, 0.f, 0.f, 0.f};
  short8 gA[4], gB[8];

  const int NKT = ISZ / 64;
  G2_STG(0);
  asm volatile("s_waitcnt vmcnt(0)" ::: "memory");
  __builtin_amdgcn_s_barrier();
  for (int s = 0; s < NKT; ++s) {
    const int rg = s & 1;
    if (s + 1 < NKT) G2_STG(s + 1);
    G2_LOADF(rg, kx0);
    asm volatile("s_waitcnt lgkmcnt(0)" ::: "memory");
    __builtin_amdgcn_sched_barrier(0);
    G2_MFMA;
    G2_LOADF(rg, kx1);
    asm volatile("s_waitcnt lgkmcnt(0)" ::: "memory");
    __builtin_amdgcn_sched_barrier(0);
    G2_MFMA;
    asm volatile("s_waitcnt vmcnt(0)" ::: "memory");
    __builtin_amdgcn_s_barrier();
  }

#pragma unroll
  for (int m = 0; m < 4; ++m) {
#pragma unroll
    for (int r = 0; r < 4; ++r) {
      const int row = brow + wm * 64 + m * 16 + fg * 4 + r;
#pragma unroll
      for (int n = 0; n < 8; ++n) {
        const int col = bcol + wn * 128 + n * 16 + fr;
        tmp[(size_t)row * HID + col] = f2bf(accf[m][n][r]);
      }
    }
  }
}

// ---------------- combine: out[t] = tmp[sh] + w0*tmp[s0] + w1*tmp[s1] -----------
__global__ __launch_bounds__(256) void k_combine(
    const u16* __restrict__ tmp, const int* __restrict__ slotmap,
    const float2* __restrict__ wts, float* __restrict__ out) {
  const int idx = blockIdx.x * 256 + threadIdx.x;
  const int t = idx >> 7;
  const int c = (idx & 127) << 3;
  const int s0 = slotmap[2 * t], s1 = slotmap[2 * t + 1];
  const float2 wv = wts[t];
  const short8 a = *(const short8*)(tmp + (size_t)s0 * HID + c);
  const short8 b = *(const short8*)(tmp + (size_t)s1 * HID + c);
  const short8 s = *(const short8*)(tmp + (size_t)(RBASE + t) * HID + c);
  float r[8];
#pragma unroll
  for (int j = 0; j < 8; ++j)
    r[j] = bf2f((u16)s[j]) + wv.x * bf2f((u16)a[j]) + wv.y * bf2f((u16)b[j]);
  float* po = out + (size_t)t * HID + c;
  *(float4*)po       = make_float4(r[0], r[1], r[2], r[3]);
  *(float4*)(po + 4) = make_float4(r[4], r[5], r[6], r[7]);
}

// ---------------- launch ----------------
extern "C" void kernel_launch(void* const* d_in, const int* in_sizes, int n_in,
                              void* d_out, int out_size, void* d_ws, size_t ws_size,
                              hipStream_t stream) {
  const float* x   = (const float*)d_in[0];
  const float* wg  = (const float*)d_in[1];
  const float* wgu = (const float*)d_in[2];
  const float* wdn = (const float*)d_in[3];
  const float* wsg = (const float*)d_in[4];
  const float* wsd = (const float*)d_in[5];
  float* out = (float*)d_out;

  char* ws = (char*)d_ws;
  i8*  xq    = (i8*)ws;   ws += (size_t)T_TOK * HID;
  i8*  wguq  = (i8*)ws;   ws += (size_t)NE * 1024 * HID;
  u16* wdT   = (u16*)ws;  ws += (size_t)NE * HID * ISZ * 2;
  u16* actb  = (u16*)ws;  ws += (size_t)NSLOT * ISZ * 2;
  u16* tmp   = (u16*)ws;  ws += (size_t)NSLOT * HID * 2;
  float* sxg = (float*)ws; ws += (size_t)T_TOK * 4;
  int* swc_i = (int*)ws;  ws += (size_t)NE * 1024 * 4;
  int* eidx  = (int*)ws;  ws += (size_t)T_TOK * 4;
  float2* wt = (float2*)ws; ws += (size_t)T_TOK * 8;
  int* btok  = (int*)ws;  ws += (size_t)RBASE * 4;
  int* smap  = (int*)ws;  ws += (size_t)2 * T_TOK * 4;
  int* seg   = (int*)ws;  ws += 16 * 4;
  int* segc  = (int*)ws;

  k_rw<<<NB_RTR + NB_WAM, 256, 0, stream>>>(
      x, wg, wgu, wsg, xq, sxg, eidx, wt, swc_i);
  k_prep2<<<NB_WGUP + NB_WDN, 256, 0, stream>>>(
      wgu, wsg, wdn, wsd, swc_i, wguq, wdT);
  k_scatter<<<1, 512, 0, stream>>>(eidx, btok, smap, seg, segc);
  k_gemm_gu<<<NROWB * 4, 512, 0, stream>>>(
      xq, wguq, seg, segc, btok, sxg, swc_i, actb);
  k_gemm_down<<<NROWB * 4, 512, 0, stream>>>(actb, wdT, seg, segc, tmp);
  k_combine<<<(T_TOK * HID / 8) / 256, 256, 0, stream>>>(tmp, smap, wt, out);
}

// Round 23
// 177.236 us; speedup vs baseline: 1.1483x; 1.0188x over previous
//
#include <hip/hip_runtime.h>
#include <hip/hip_bf16.h>
#include <cstdint>

#define T_TOK 8192
#define HID   1024
#define NE    9
#define ISZ   512
#define RBASE 18432
#define NSLOT (RBASE + T_TOK)   // 26624

#define BM 256
#define NROWB (NSLOT / BM)      // 104

typedef unsigned short u16;
typedef unsigned int   u32;
typedef signed char    i8;
typedef __attribute__((ext_vector_type(8))) short short8;
typedef __attribute__((ext_vector_type(4))) float f32x4;
typedef __attribute__((ext_vector_type(4))) int   i32x4;

__device__ __forceinline__ u16 f2bf(float f) {
  u32 u = __builtin_bit_cast(u32, f);
  return (u16)((u + 0x7fffu + ((u >> 16) & 1u)) >> 16);
}
__device__ __forceinline__ float bf2f(u16 v) {
  return __builtin_bit_cast(float, (u32)v << 16);
}
__device__ __forceinline__ int q8(float v, float inv) {
  int q = (int)__builtin_rintf(v * inv);
  return (q > 127) ? 127 : ((q < -127) ? -127 : q);
}
__device__ __forceinline__ int colp_of(int c) {
  int i = (c < 512) ? c : (c - 512);
  return (i >> 4) * 32 + ((c < 512) ? 0 : 16) + (i & 15);
}

#define STAGE(gp, lp) __builtin_amdgcn_global_load_lds( \
    (__attribute__((address_space(1))) u32*)(gp),       \
    (__attribute__((address_space(3))) u32*)(lp), 16, 0, 0)

// ---------------- k_rw: router (cold x) + per-column wamax (cold wgu), fused ----
#define NB_RTR  (T_TOK / 4)  // 2048
#define NB_WAM  (64 * NE)    // 576

__global__ __launch_bounds__(256) void k_rw(
    const float* __restrict__ x, const float* __restrict__ wg,
    const float* __restrict__ wgu, const float* __restrict__ wsg,
    i8* __restrict__ xq, float* __restrict__ sxg,
    int* __restrict__ eidx, float2* __restrict__ wts,
    int* __restrict__ swc_i) {
  const int b = blockIdx.x;
  const int tid = threadIdx.x;

  if (b >= NB_RTR) {
    const int flat = b - NB_RTR;
    const int e = flat >> 6, hb = flat & 63;
    const float* src = (e < 8) ? (wgu + (size_t)e * 1048576) : wsg;
    const int wv = tid >> 6, l = tid & 63;
    float4 m4[4];
#pragma unroll
    for (int j = 0; j < 4; ++j) m4[j] = make_float4(0.f, 0.f, 0.f, 0.f);
    const int r0 = hb * 16 + wv * 4;
#pragma unroll
    for (int r = 0; r < 4; ++r) {
      const float* row = src + (size_t)(r0 + r) * 1024;
#pragma unroll
      for (int j = 0; j < 4; ++j) {
        const float4 v = *(const float4*)&row[j * 256 + l * 4];
        m4[j].x = fmaxf(m4[j].x, fabsf(v.x));
        m4[j].y = fmaxf(m4[j].y, fabsf(v.y));
        m4[j].z = fmaxf(m4[j].z, fabsf(v.z));
        m4[j].w = fmaxf(m4[j].w, fabsf(v.w));
      }
    }
    __shared__ float4 red[4][4][64];
#pragma unroll
    for (int j = 0; j < 4; ++j) red[wv][j][l] = m4[j];
    __syncthreads();
    const int j2 = tid >> 6, l2 = tid & 63;
    const float4 a = red[0][j2][l2], bb = red[1][j2][l2];
    const float4 c = red[2][j2][l2], d = red[3][j2][l2];
    float o[4];
    o[0] = fmaxf(fmaxf(a.x, bb.x), fmaxf(c.x, d.x));
    o[1] = fmaxf(fmaxf(a.y, bb.y), fmaxf(c.y, d.y));
    o[2] = fmaxf(fmaxf(a.z, bb.z), fmaxf(c.z, d.z));
    o[3] = fmaxf(fmaxf(a.w, bb.w), fmaxf(c.w, d.w));
    const int cbase = j2 * 256 + l2 * 4;
#pragma unroll
    for (int k = 0; k < 4; ++k)
      atomicMax(&swc_i[e * 1024 + colp_of(cbase + k)], __float_as_int(o[k]));
    return;
  }

  const int t = b * 4 + (tid >> 6);
  const int l = tid & 63;
  float a[8] = {0, 0, 0, 0, 0, 0, 0, 0};
  float vals[16];
  float am = 0.f;
  const float* xr = x + (size_t)t * HID;
#pragma unroll
  for (int j = 0; j < 16; ++j) {
    const int h = j * 64 + l;
    const float xv = xr[h];
    vals[j] = xv;
    am = fmaxf(am, fabsf(xv));
    const float4 w0 = *(const float4*)&wg[h * 8];
    const float4 w1 = *(const float4*)&wg[h * 8 + 4];
    a[0] += xv * w0.x; a[1] += xv * w0.y; a[2] += xv * w0.z; a[3] += xv * w0.w;
    a[4] += xv * w1.x; a[5] += xv * w1.y; a[6] += xv * w1.z; a[7] += xv * w1.w;
  }
#pragma unroll
  for (int off = 32; off >= 1; off >>= 1) {
    am = fmaxf(am, __shfl_xor(am, off));
#pragma unroll
    for (int e2 = 0; e2 < 8; ++e2) a[e2] += __shfl_xor(a[e2], off);
  }
  const float inv = (am > 0.f) ? 127.f / am : 0.f;
  i8* xqr = xq + (size_t)t * HID;
#pragma unroll
  for (int j = 0; j < 16; ++j)
    xqr[j * 64 + l] = (i8)q8(vals[j], inv);
  if (l == 0) {
    sxg[t] = am * (1.f / 127.f);
    int ia = 0;
#pragma unroll
    for (int e2 = 1; e2 < 8; ++e2) if (a[e2] > a[ia]) ia = e2;
    int ib = (ia == 0) ? 1 : 0;
#pragma unroll
    for (int e2 = 0; e2 < 8; ++e2) if (e2 != ia && a[e2] > a[ib]) ib = e2;
    float wa = 1.f / (1.f + expf(a[ib] - a[ia]));
    eidx[t] = ia | (ib << 8);
    wts[t] = make_float2(wa, 1.f - wa);
  }
}

// ---------------- k_prep2: wide-tile weight transposes only ----------------
#define NB_WGUP (128 * NE)   // 1152
#define NB_WDN  (64 * NE)    // 576

__global__ __launch_bounds__(256) void k_prep2(
    const float* __restrict__ wgu, const float* __restrict__ wsg,
    const float* __restrict__ wdn, const float* __restrict__ wsd,
    const int* __restrict__ swc_i,
    i8* __restrict__ wguq, u16* __restrict__ wdT) {
  __shared__ float tile[64][130];
  const int b = blockIdx.x;
  const int tid = threadIdx.x;

  if (b < NB_WGUP) {
    const int e = b / 128, rem = b % 128;
    const int c0 = (rem & 15) * 64, h0 = (rem >> 4) * 128;
    const float* src = (e < 8) ? (wgu + (size_t)e * HID * 1024) : wsg;
    const int hl = tid >> 1, cb = (tid & 1) * 32;
    float4 v[8];
#pragma unroll
    for (int j = 0; j < 8; ++j)
      v[j] = *(const float4*)&src[(size_t)(h0 + hl) * 1024 + c0 + cb + j * 4];
#pragma unroll
    for (int j = 0; j < 8; ++j) {
      tile[cb + j * 4 + 0][hl] = v[j].x;
      tile[cb + j * 4 + 1][hl] = v[j].y;
      tile[cb + j * 4 + 2][hl] = v[j].z;
      tile[cb + j * 4 + 3][hl] = v[j].w;
    }
    __syncthreads();
    const int cl = tid >> 2, hb = (tid & 3) * 32;
    const int cp = colp_of(c0 + cl);
    const float inv = 127.f / __int_as_float(swc_i[e * 1024 + cp]);
    i8 out[32];
#pragma unroll
    for (int k = 0; k < 32; ++k) out[k] = (i8)q8(tile[cl][hb + k], inv);
    i8* dst = &wguq[((size_t)e * 1024 + cp) * 1024 + h0 + hb];
    *(int4*)dst = *(int4*)out;
    *(int4*)(dst + 16) = *(int4*)(out + 16);
    return;
  }
  const int bb = b - NB_WGUP;
  const int e = bb / 64, rem = bb % 64;
  const int h0 = (rem & 15) * 64, i0 = (rem >> 4) * 128;
  const float* src = (e < 8) ? (wdn + (size_t)e * ISZ * HID) : wsd;
  const int il = tid >> 1, hb = (tid & 1) * 32;
  float4 v[8];
#pragma unroll
  for (int j = 0; j < 8; ++j)
    v[j] = *(const float4*)&src[(size_t)(i0 + il) * 1024 + h0 + hb + j * 4];
#pragma unroll
  for (int j = 0; j < 8; ++j) {
    tile[hb + j * 4 + 0][il] = v[j].x;
    tile[hb + j * 4 + 1][il] = v[j].y;
    tile[hb + j * 4 + 2][il] = v[j].z;
    tile[hb + j * 4 + 3][il] = v[j].w;
  }
  __syncthreads();
  const int hl = tid >> 2, ib = (tid & 3) * 32;
  u16 ob[32];
#pragma unroll
  for (int k = 0; k < 32; ++k) ob[k] = f2bf(tile[hl][ib + k]);
  u16* dst = &wdT[((size_t)e * HID + h0 + hl) * ISZ + i0 + ib];
  *(int4*)dst        = *(int4*)ob;
  *(int4*)(dst + 8)  = *(int4*)(ob + 8);
  *(int4*)(dst + 16) = *(int4*)(ob + 16);
  *(int4*)(dst + 24) = *(int4*)(ob + 24);
}

// ---------------- deterministic counting scatter (256-aligned segments) --------
__global__ __launch_bounds__(512) void k_scatter(
    const int* __restrict__ eidx, int* __restrict__ btok, int* __restrict__ slotmap,
    int* __restrict__ seg, int* __restrict__ segcnt) {
  __shared__ int cnt_s[8];
  __shared__ int goff_s[9];
  const int e = threadIdx.x >> 6;
  const int l = threadIdx.x & 63;

  int c1 = 0;
  for (int c = 0; c < T_TOK / 64; ++c) {
    int v = eidx[c * 64 + l];
    c1 += __popcll(__ballot((v & 255) == e)) + __popcll(__ballot(((v >> 8) & 255) == e));
  }
  if (l == 0) cnt_s[e] = c1;
  __syncthreads();
  if (threadIdx.x == 0) {
    int off = 0;
    for (int k = 0; k < 8; ++k) { goff_s[k] = off; off += (cnt_s[k] + 255) & ~255; }
    goff_s[8] = off;
  }
  __syncthreads();
  const int base0 = goff_s[e];
  const int cnt_e = cnt_s[e];
  const unsigned long long below = (l == 63) ? ~0ull >> 1 : ((1ull << l) - 1);

  int base = base0;
  for (int c = 0; c < T_TOK / 64; ++c) {
    const int t = c * 64 + l;
    const int v = eidx[t];
    const unsigned long long ma = __ballot((v & 255) == e);
    const unsigned long long mb = __ballot(((v >> 8) & 255) == e);
    if ((v & 255) == e) {
      int s = base + __popcll(ma & below);
      btok[s] = t; slotmap[2 * t] = s;
    }
    if (((v >> 8) & 255) == e) {
      int s = base + __popcll(ma) + __popcll(mb & below);
      btok[s] = t; slotmap[2 * t + 1] = s;
    }
    base += __popcll(ma) + __popcll(mb);
  }
  for (int p = cnt_e + l; p < ((cnt_e + 255) & ~255); p += 64) btok[base0 + p] = 0;
  if (threadIdx.x < 9) seg[threadIdx.x] = goff_s[threadIdx.x];
  if (threadIdx.x < 8) segcnt[threadIdx.x] = cnt_s[threadIdx.x];
}

__device__ __forceinline__ bool seg_lookup(const int* __restrict__ seg,
                                           const int* __restrict__ segcnt,
                                           int brow, int& e) {
  if (brow >= RBASE) { e = 8; return true; }
  if (brow >= seg[8]) return false;
  e = 0;
#pragma unroll
  for (int k = 1; k < 8; ++k) if (brow >= seg[k]) e = k;
  return brow < seg[e] + segcnt[e];
}

// =================================================================================
// GEMM1 (int8): 256x256 tile, K-slot=128 i8, 8 waves 4M x 2N (per-wave 64x128).
// LDS 160 KiB: A 3-ring (3x32KB) + B 2-ring (2x32KB). Per slot: issue B(s+1)
// then A(s+2); end-of-slot vmcnt(4) keeps A(s+2) in flight (never drains
// mid-loop). ^(row&7) swizzle (0 conflicts). Scales staged into dead ring
// space after the K loop. K order identical to r22 -> bit-identical output.
// =================================================================================

#define G1_STG_A(kt) do { i8* _d = Alds + ((kt) % 3) * 32768 + w * 1024; \
    STAGE(sA0 + (kt) * 128, _d);                                         \
    STAGE(sA1 + (kt) * 128, _d + 8192);                                  \
    STAGE(sA2 + (kt) * 128, _d + 16384);                                 \
    STAGE(sA3 + (kt) * 128, _d + 24576); } while (0)
#define G1_STG_B(kt) do { i8* _d = Blds + ((kt) & 1) * 32768 + w * 1024; \
    STAGE(sB0 + (kt) * 128, _d);                                         \
    STAGE(sB1 + (kt) * 128, _d + 8192);                                  \
    STAGE(sB2 + (kt) * 128, _d + 16384);                                 \
    STAGE(sB3 + (kt) * 128, _d + 24576); } while (0)

#define G1_LOADF(AR, BR, KX) do {                                        \
    _Pragma("unroll") for (int m = 0; m < 4; ++m)                        \
      fA[m] = *(const i32x4*)&Alds[(AR) * 32768 + aBase + m * 2048 + (KX)]; \
    _Pragma("unroll") for (int n = 0; n < 8; ++n)                        \
      fB[n] = *(const i32x4*)&Blds[(BR) * 32768 + bBase + n * 2048 + (KX)]; } while (0)

#define G1_MFMA do { __builtin_amdgcn_s_setprio(1);                      \
    _Pragma("unroll") for (int m = 0; m < 4; ++m)                        \
      _Pragma("unroll") for (int n = 0; n < 8; ++n)                      \
        acc[m][n] = __builtin_amdgcn_mfma_i32_16x16x64_i8(fA[m], fB[n], acc[m][n], 0, 0, 0); \
    __builtin_amdgcn_s_setprio(0); } while (0)

__global__ __launch_bounds__(512) void k_gemm_gu(
    const i8* __restrict__ xq, const i8* __restrict__ wguq,
    const int* __restrict__ seg, const int* __restrict__ segcnt,
    const int* __restrict__ btok, const float* __restrict__ sxg,
    const int* __restrict__ swc_i,
    u16* __restrict__ act)
{
  const int bid = blockIdx.x;
  const int brow = (bid % NROWB) * BM;
  const int bcol = (bid / NROWB) * 256;
  int e;
  if (!seg_lookup(seg, segcnt, brow, e)) return;

  __shared__ __align__(16) i8 lds[163840];   // 160 KiB: A 3-ring + B 2-ring
  i8* const Alds = lds;
  i8* const Blds = lds + 98304;

  const int tid = threadIdx.x;
  const int w = tid >> 6, l = tid & 63;
  const int wm = w >> 1, wn = w & 1;
  const int fr = l & 15, fg = l >> 4;

  const int rr = w * 8 + (l >> 3);
  const int sw = ((l & 7) ^ (l >> 3)) * 16;
  int tr[4];
#pragma unroll
  for (int j = 0; j < 4; ++j) {
    const int gr = brow + j * 64 + rr;
    tr[j] = (e < 8) ? btok[gr] : (gr - RBASE);
  }
  const i8* sA0 = xq + (size_t)tr[0] * HID + sw;
  const i8* sA1 = xq + (size_t)tr[1] * HID + sw;
  const i8* sA2 = xq + (size_t)tr[2] * HID + sw;
  const i8* sA3 = xq + (size_t)tr[3] * HID + sw;
  const i8* sB0 = wguq + ((size_t)e * 1024 + bcol + 0 * 64 + rr) * HID + sw;
  const i8* sB1 = wguq + ((size_t)e * 1024 + bcol + 1 * 64 + rr) * HID + sw;
  const i8* sB2 = wguq + ((size_t)e * 1024 + bcol + 2 * 64 + rr) * HID + sw;
  const i8* sB3 = wguq + ((size_t)e * 1024 + bcol + 3 * 64 + rr) * HID + sw;

  const int aBase = (wm * 64 + fr) * 128;
  const int bBase = (wn * 128 + fr) * 128;
  const int kx0 = (fg ^ (fr & 7)) * 16;
  const int kx1 = kx0 ^ 64;

  i32x4 acc[4][8];
#pragma unroll
  for (int m = 0; m < 4; ++m)
#pragma unroll
    for (int n = 0; n < 8; ++n) acc[m][n] = (i32x4){0, 0, 0, 0};
  i32x4 fA[4], fB[8];

  const int NKT = HID / 128;   // 8 slots
  // prologue: A(0), B(0), A(1); wait leaves A(1)'s 4 loads in flight
  G1_STG_A(0); G1_STG_B(0); G1_STG_A(1);
  asm volatile("s_waitcnt vmcnt(4)" ::: "memory");
  __builtin_amdgcn_s_barrier();
  for (int s = 0; s < NKT; ++s) {
    if (s + 1 < NKT) G1_STG_B(s + 1);      // B first (must complete by slot end)
    if (s + 2 < NKT) G1_STG_A(s + 2);      // A last (stays in flight)
    const int ar = s % 3, br = s & 1;
    G1_LOADF(ar, br, kx0);
    asm volatile("s_waitcnt lgkmcnt(0)" ::: "memory");
    __builtin_amdgcn_sched_barrier(0);
    G1_MFMA;
    G1_LOADF(ar, br, kx1);
    asm volatile("s_waitcnt lgkmcnt(0)" ::: "memory");
    __builtin_amdgcn_sched_barrier(0);
    G1_MFMA;
    if (s + 2 < NKT) { asm volatile("s_waitcnt vmcnt(4)" ::: "memory"); }
    else             { asm volatile("s_waitcnt vmcnt(0)" ::: "memory"); }
    __builtin_amdgcn_s_barrier();
  }

  // stage scales into now-dead ring space
  float* sxl  = (float*)lds;
  float* swcl = (float*)(lds + 2048);
  if (tid < BM) {
    const int rrow = brow + tid;
    const int tk = (e < 8) ? btok[rrow] : (rrow - RBASE);
    sxl[tid] = sxg[tk];
  } else {
    swcl[tid - 256] = __int_as_float(swc_i[e * 1024 + bcol + (tid - 256)]) * (1.f / 127.f);
  }
  __syncthreads();

#pragma unroll
  for (int m = 0; m < 4; ++m) {
#pragma unroll
    for (int p = 0; p < 4; ++p) {
      const i32x4 gI = acc[m][2 * p], uI = acc[m][2 * p + 1];
      const int col = ((bcol + wn * 128) >> 1) + p * 16 + fr;
      const float swg = swcl[wn * 128 + p * 32 + fr];
      const float swu = swcl[wn * 128 + p * 32 + 16 + fr];
#pragma unroll
      for (int r = 0; r < 4; ++r) {
        const int row_l = wm * 64 + m * 16 + fg * 4 + r;
        const float sx = sxl[row_l];
        const float gate = (float)gI[r] * (sx * swg);
        const float up   = (float)uI[r] * (sx * swu);
        const float sv = gate / (1.f + __expf(-gate));
        act[(size_t)(brow + row_l) * ISZ + col] = f2bf(sv * up);
      }
    }
  }
}

// =================================================================================
// GEMM2 (bf16): mirror. K-slot=64 bf16, A 3-ring + B 2-ring (5 x 32 KB = 160 KiB),
// counted vmcnt(4), ^(row&7) swizzle. K order identical to r22.
// =================================================================================

#define G2_STG_A(kt) do { u16* _d = Alds2 + ((kt) % 3) * 16384 + w * 512; \
    STAGE(dA0 + (kt) * 64, _d);                                           \
    STAGE(dA1 + (kt) * 64, _d + 4096);                                    \
    STAGE(dA2 + (kt) * 64, _d + 8192);                                    \
    STAGE(dA3 + (kt) * 64, _d + 12288); } while (0)
#define G2_STG_B(kt) do { u16* _d = Blds2 + ((kt) & 1) * 16384 + w * 512; \
    STAGE(dB0 + (kt) * 64, _d);                                           \
    STAGE(dB1 + (kt) * 64, _d + 4096);                                    \
    STAGE(dB2 + (kt) * 64, _d + 8192);                                    \
    STAGE(dB3 + (kt) * 64, _d + 12288); } while (0)

#define G2_LOADF(AR, BR, KX) do {                                         \
    _Pragma("unroll") for (int m = 0; m < 4; ++m)                         \
      gA[m] = *(const short8*)&Alds2[(AR) * 16384 + aBase + m * 1024 + (KX)]; \
    _Pragma("unroll") for (int n = 0; n < 8; ++n)                         \
      gB[n] = *(const short8*)&Blds2[(BR) * 16384 + bBase + n * 1024 + (KX)]; } while (0)

#define G2_MFMA do { __builtin_amdgcn_s_setprio(1);                       \
    _Pragma("unroll") for (int m = 0; m < 4; ++m)                         \
      _Pragma("unroll") for (int n = 0; n < 8; ++n)                       \
        accf[m][n] = __builtin_amdgcn_mfma_f32_16x16x32_bf16(gA[m], gB[n], accf[m][n], 0, 0, 0); \
    __builtin_amdgcn_s_setprio(0); } while (0)

__global__ __launch_bounds__(512) void k_gemm_down(
    const u16* __restrict__ act, const u16* __restrict__ wdT,
    const int* __restrict__ seg, const int* __restrict__ segcnt,
    u16* __restrict__ tmp) {
  const int bid = blockIdx.x;
  const int brow = (bid % NROWB) * BM;
  const int bcol = (bid / NROWB) * 256;
  int e;
  if (!seg_lookup(seg, segcnt, brow, e)) return;

  __shared__ __align__(16) u16 lds2[81920];   // 160 KiB: A 3-ring + B 2-ring
  u16* const Alds2 = lds2;
  u16* const Blds2 = lds2 + 49152;

  const int tid = threadIdx.x;
  const int w = tid >> 6, l = tid & 63;
  const int wm = w >> 1, wn = w & 1;
  const int fr = l & 15, fg = l >> 4;

  const int rr = w * 8 + (l >> 3);
  const int sw = ((l & 7) ^ (l >> 3)) * 8;
  const u16* dA0 = act + (size_t)(brow + 0 * 64 + rr) * ISZ + sw;
  const u16* dA1 = act + (size_t)(brow + 1 * 64 + rr) * ISZ + sw;
  const u16* dA2 = act + (size_t)(brow + 2 * 64 + rr) * ISZ + sw;
  const u16* dA3 = act + (size_t)(brow + 3 * 64 + rr) * ISZ + sw;
  const u16* dB0 = wdT + ((size_t)e * 1024 + bcol + 0 * 64 + rr) * ISZ + sw;
  const u16* dB1 = wdT + ((size_t)e * 1024 + bcol + 1 * 64 + rr) * ISZ + sw;
  const u16* dB2 = wdT + ((size_t)e * 1024 + bcol + 2 * 64 + rr) * ISZ + sw;
  const u16* dB3 = wdT + ((size_t)e * 1024 + bcol + 3 * 64 + rr) * ISZ + sw;

  const int aBase = (wm * 64 + fr) * 64;
  const int bBase = (wn * 128 + fr) * 64;
  const int kx0 = (fg ^ (fr & 7)) * 8;
  const int kx1 = kx0 ^ 32;

  f32x4 accf[4][8];
#pragma unroll
  for (int m = 0; m < 4; ++m)
#pragma unroll
    for (int n = 0; n < 8; ++n) accf[m][n] = (f32x4){0.f, 0.f, 0.f, 0.f};
  short8 gA[4], gB[8];

  const int NKT = ISZ / 64;   // 8 slots
  G2_STG_A(0); G2_STG_B(0); G2_STG_A(1);
  asm volatile("s_waitcnt vmcnt(4)" ::: "memory");
  __builtin_amdgcn_s_barrier();
  for (int s = 0; s < NKT; ++s) {
    if (s + 1 < NKT) G2_STG_B(s + 1);
    if (s + 2 < NKT) G2_STG_A(s + 2);
    const int ar = s % 3, br = s & 1;
    G2_LOADF(ar, br, kx0);
    asm volatile("s_waitcnt lgkmcnt(0)" ::: "memory");
    __builtin_amdgcn_sched_barrier(0);
    G2_MFMA;
    G2_LOADF(ar, br, kx1);
    asm volatile("s_waitcnt lgkmcnt(0)" ::: "memory");
    __builtin_amdgcn_sched_barrier(0);
    G2_MFMA;
    if (s + 2 < NKT) { asm volatile("s_waitcnt vmcnt(4)" ::: "memory"); }
    else             { asm volatile("s_waitcnt vmcnt(0)" ::: "memory"); }
    __builtin_amdgcn_s_barrier();
  }

#pragma unroll
  for (int m = 0; m < 4; ++m) {
#pragma unroll
    for (int r = 0; r < 4; ++r) {
      const int row = brow + wm * 64 + m * 16 + fg * 4 + r;
#pragma unroll
      for (int n = 0; n < 8; ++n) {
        const int col = bcol + wn * 128 + n * 16 + fr;
        tmp[(size_t)row * HID + col] = f2bf(accf[m][n][r]);
      }
    }
  }
}

// ---------------- combine: out[t] = tmp[sh] + w0*tmp[s0] + w1*tmp[s1] -----------
__global__ __launch_bounds__(256) void k_combine(
    const u16* __restrict__ tmp, const int* __restrict__ slotmap,
    const float2* __restrict__ wts, float* __restrict__ out) {
  const int idx = blockIdx.x * 256 + threadIdx.x;
  const int t = idx >> 7;
  const int c = (idx & 127) << 3;
  const int s0 = slotmap[2 * t], s1 = slotmap[2 * t + 1];
  const float2 wv = wts[t];
  const short8 a = *(const short8*)(tmp + (size_t)s0 * HID + c);
  const short8 b = *(const short8*)(tmp + (size_t)s1 * HID + c);
  const short8 s = *(const short8*)(tmp + (size_t)(RBASE + t) * HID + c);
  float r[8];
#pragma unroll
  for (int j = 0; j < 8; ++j)
    r[j] = bf2f((u16)s[j]) + wv.x * bf2f((u16)a[j]) + wv.y * bf2f((u16)b[j]);
  float* po = out + (size_t)t * HID + c;
  *(float4*)po       = make_float4(r[0], r[1], r[2], r[3]);
  *(float4*)(po + 4) = make_float4(r[4], r[5], r[6], r[7]);
}

// ---------------- launch ----------------
extern "C" void kernel_launch(void* const* d_in, const int* in_sizes, int n_in,
                              void* d_out, int out_size, void* d_ws, size_t ws_size,
                              hipStream_t stream) {
  const float* x   = (const float*)d_in[0];
  const float* wg  = (const float*)d_in[1];
  const float* wgu = (const float*)d_in[2];
  const float* wdn = (const float*)d_in[3];
  const float* wsg = (const float*)d_in[4];
  const float* wsd = (const float*)d_in[5];
  float* out = (float*)d_out;

  char* ws = (char*)d_ws;
  i8*  xq    = (i8*)ws;   ws += (size_t)T_TOK * HID;
  i8*  wguq  = (i8*)ws;   ws += (size_t)NE * 1024 * HID;
  u16* wdT   = (u16*)ws;  ws += (size_t)NE * HID * ISZ * 2;
  u16* actb  = (u16*)ws;  ws += (size_t)NSLOT * ISZ * 2;
  u16* tmp   = (u16*)ws;  ws += (size_t)NSLOT * HID * 2;
  float* sxg = (float*)ws; ws += (size_t)T_TOK * 4;
  int* swc_i = (int*)ws;  ws += (size_t)NE * 1024 * 4;
  int* eidx  = (int*)ws;  ws += (size_t)T_TOK * 4;
  float2* wt = (float2*)ws; ws += (size_t)T_TOK * 8;
  int* btok  = (int*)ws;  ws += (size_t)RBASE * 4;
  int* smap  = (int*)ws;  ws += (size_t)2 * T_TOK * 4;
  int* seg   = (int*)ws;  ws += 16 * 4;
  int* segc  = (int*)ws;

  k_rw<<<NB_RTR + NB_WAM, 256, 0, stream>>>(
      x, wg, wgu, wsg, xq, sxg, eidx, wt, swc_i);
  k_prep2<<<NB_WGUP + NB_WDN, 256, 0, stream>>>(
      wgu, wsg, wdn, wsd, swc_i, wguq, wdT);
  k_scatter<<<1, 512, 0, stream>>>(eidx, btok, smap, seg, segc);
  k_gemm_gu<<<NROWB * 4, 512, 0, stream>>>(
      xq, wguq, seg, segc, btok, sxg, swc_i, actb);
  k_gemm_down<<<NROWB * 4, 512, 0, stream>>>(actb, wdT, seg, segc, tmp);
  k_combine<<<(T_TOK * HID / 8) / 256, 256, 0, stream>>>(tmp, smap, wt, out);
}

// Round 24
// 175.136 us; speedup vs baseline: 1.1621x; 1.0120x over previous
//
#include <hip/hip_runtime.h>
#include <hip/hip_bf16.h>
#include <cstdint>

#define T_TOK 8192
#define HID   1024
#define NE    9
#define ISZ   512
#define RBASE 18432
#define NSLOT (RBASE + T_TOK)   // 26624

#define BM 256
#define NROWB (NSLOT / BM)      // 104

typedef unsigned short u16;
typedef unsigned int   u32;
typedef signed char    i8;
typedef __attribute__((ext_vector_type(8))) short short8;
typedef __attribute__((ext_vector_type(4))) float f32x4;
typedef __attribute__((ext_vector_type(4))) int   i32x4;

__device__ __forceinline__ u16 f2bf(float f) {
  u32 u = __builtin_bit_cast(u32, f);
  return (u16)((u + 0x7fffu + ((u >> 16) & 1u)) >> 16);
}
__device__ __forceinline__ float bf2f(u16 v) {
  return __builtin_bit_cast(float, (u32)v << 16);
}
__device__ __forceinline__ int q8(float v, float inv) {
  int q = (int)__builtin_rintf(v * inv);
  return (q > 127) ? 127 : ((q < -127) ? -127 : q);
}
__device__ __forceinline__ int colp_of(int c) {
  int i = (c < 512) ? c : (c - 512);
  return (i >> 4) * 32 + ((c < 512) ? 0 : 16) + (i & 15);
}

#define STAGE(gp, lp) __builtin_amdgcn_global_load_lds( \
    (__attribute__((address_space(1))) u32*)(gp),       \
    (__attribute__((address_space(3))) u32*)(lp), 16, 0, 0)

// ---------------- k_rw: router + wamax + wdn-cvt (all independent, fused) -------
#define NB_RTR  (T_TOK / 4)  // 2048
#define NB_WAM  (64 * NE)    // 576
#define NB_WDN  (64 * NE)    // 576

__global__ __launch_bounds__(256) void k_rw(
    const float* __restrict__ x, const float* __restrict__ wg,
    const float* __restrict__ wgu, const float* __restrict__ wsg,
    const float* __restrict__ wdn, const float* __restrict__ wsd,
    i8* __restrict__ xq, float* __restrict__ sxg,
    int* __restrict__ eidx, float2* __restrict__ wts,
    int* __restrict__ swc_i, u16* __restrict__ wdT) {
  __shared__ __align__(16) char shm[33280];   // union: red (16KB) | tile (33KB)
  const int b = blockIdx.x;
  const int tid = threadIdx.x;

  if (b >= NB_RTR + NB_WAM) {
    // ---- wdn transpose: 128i x 64h tile -> bf16 [e][h][i] (independent) ----
    float (*tile)[130] = (float(*)[130])shm;
    const int flat = b - NB_RTR - NB_WAM;
    const int e = flat / 64, rem = flat % 64;
    const int h0 = (rem & 15) * 64, i0 = (rem >> 4) * 128;
    const float* src = (e < 8) ? (wdn + (size_t)e * ISZ * HID) : wsd;
    const int il = tid >> 1, hb = (tid & 1) * 32;
    float4 v[8];
#pragma unroll
    for (int j = 0; j < 8; ++j)
      v[j] = *(const float4*)&src[(size_t)(i0 + il) * 1024 + h0 + hb + j * 4];
#pragma unroll
    for (int j = 0; j < 8; ++j) {
      tile[hb + j * 4 + 0][il] = v[j].x;
      tile[hb + j * 4 + 1][il] = v[j].y;
      tile[hb + j * 4 + 2][il] = v[j].z;
      tile[hb + j * 4 + 3][il] = v[j].w;
    }
    __syncthreads();
    const int hl = tid >> 2, ib = (tid & 3) * 32;
    u16 ob[32];
#pragma unroll
    for (int k = 0; k < 32; ++k) ob[k] = f2bf(tile[hl][ib + k]);
    u16* dst = &wdT[((size_t)e * HID + h0 + hl) * ISZ + i0 + ib];
    *(int4*)dst        = *(int4*)ob;
    *(int4*)(dst + 8)  = *(int4*)(ob + 8);
    *(int4*)(dst + 16) = *(int4*)(ob + 16);
    *(int4*)(dst + 24) = *(int4*)(ob + 24);
    return;
  }

  if (b >= NB_RTR) {
    // ---- wamax: block = 16 rows x 1024 cols of expert e; atomicMax (det.) ----
    float4 (*red)[4][64] = (float4(*)[4][64])shm;
    const int flat = b - NB_RTR;
    const int e = flat >> 6, hb = flat & 63;
    const float* src = (e < 8) ? (wgu + (size_t)e * 1048576) : wsg;
    const int wv = tid >> 6, l = tid & 63;
    float4 m4[4];
#pragma unroll
    for (int j = 0; j < 4; ++j) m4[j] = make_float4(0.f, 0.f, 0.f, 0.f);
    const int r0 = hb * 16 + wv * 4;
#pragma unroll
    for (int r = 0; r < 4; ++r) {
      const float* row = src + (size_t)(r0 + r) * 1024;
#pragma unroll
      for (int j = 0; j < 4; ++j) {
        const float4 v = *(const float4*)&row[j * 256 + l * 4];
        m4[j].x = fmaxf(m4[j].x, fabsf(v.x));
        m4[j].y = fmaxf(m4[j].y, fabsf(v.y));
        m4[j].z = fmaxf(m4[j].z, fabsf(v.z));
        m4[j].w = fmaxf(m4[j].w, fabsf(v.w));
      }
    }
#pragma unroll
    for (int j = 0; j < 4; ++j) red[wv][j][l] = m4[j];
    __syncthreads();
    const int j2 = tid >> 6, l2 = tid & 63;
    const float4 a = red[0][j2][l2], bb = red[1][j2][l2];
    const float4 c = red[2][j2][l2], d = red[3][j2][l2];
    float o[4];
    o[0] = fmaxf(fmaxf(a.x, bb.x), fmaxf(c.x, d.x));
    o[1] = fmaxf(fmaxf(a.y, bb.y), fmaxf(c.y, d.y));
    o[2] = fmaxf(fmaxf(a.z, bb.z), fmaxf(c.z, d.z));
    o[3] = fmaxf(fmaxf(a.w, bb.w), fmaxf(c.w, d.w));
    const int cbase = j2 * 256 + l2 * 4;
#pragma unroll
    for (int k = 0; k < 4; ++k)
      atomicMax(&swc_i[e * 1024 + colp_of(cbase + k)], __float_as_int(o[k]));
    return;
  }

  // ---- router: 4 tokens/block, 1 wave/token; coalesced wg rows ----
  const int t = b * 4 + (tid >> 6);
  const int l = tid & 63;
  float a[8] = {0, 0, 0, 0, 0, 0, 0, 0};
  float vals[16];
  float am = 0.f;
  const float* xr = x + (size_t)t * HID;
#pragma unroll
  for (int j = 0; j < 16; ++j) {
    const int h = j * 64 + l;
    const float xv = xr[h];
    vals[j] = xv;
    am = fmaxf(am, fabsf(xv));
    const float4 w0 = *(const float4*)&wg[h * 8];
    const float4 w1 = *(const float4*)&wg[h * 8 + 4];
    a[0] += xv * w0.x; a[1] += xv * w0.y; a[2] += xv * w0.z; a[3] += xv * w0.w;
    a[4] += xv * w1.x; a[5] += xv * w1.y; a[6] += xv * w1.z; a[7] += xv * w1.w;
  }
#pragma unroll
  for (int off = 32; off >= 1; off >>= 1) {
    am = fmaxf(am, __shfl_xor(am, off));
#pragma unroll
    for (int e2 = 0; e2 < 8; ++e2) a[e2] += __shfl_xor(a[e2], off);
  }
  const float inv = (am > 0.f) ? 127.f / am : 0.f;
  i8* xqr = xq + (size_t)t * HID;
#pragma unroll
  for (int j = 0; j < 16; ++j)
    xqr[j * 64 + l] = (i8)q8(vals[j], inv);
  if (l == 0) {
    sxg[t] = am * (1.f / 127.f);
    int ia = 0;
#pragma unroll
    for (int e2 = 1; e2 < 8; ++e2) if (a[e2] > a[ia]) ia = e2;
    int ib = (ia == 0) ? 1 : 0;
#pragma unroll
    for (int e2 = 0; e2 < 8; ++e2) if (e2 != ia && a[e2] > a[ib]) ib = e2;
    float wa = 1.f / (1.f + expf(a[ib] - a[ia]));
    eidx[t] = ia | (ib << 8);
    wts[t] = make_float2(wa, 1.f - wa);
  }
}

// ---------------- k_prep2: wgup quant-transpose only ----------------
#define NB_WGUP (128 * NE)   // 1152

__global__ __launch_bounds__(256) void k_prep2(
    const float* __restrict__ wgu, const float* __restrict__ wsg,
    const int* __restrict__ swc_i, i8* __restrict__ wguq) {
  __shared__ float tile[64][130];
  const int b = blockIdx.x;
  const int tid = threadIdx.x;

  const int e = b / 128, rem = b % 128;
  const int c0 = (rem & 15) * 64, h0 = (rem >> 4) * 128;
  const float* src = (e < 8) ? (wgu + (size_t)e * HID * 1024) : wsg;
  const int hl = tid >> 1, cb = (tid & 1) * 32;
  float4 v[8];
#pragma unroll
  for (int j = 0; j < 8; ++j)
    v[j] = *(const float4*)&src[(size_t)(h0 + hl) * 1024 + c0 + cb + j * 4];
#pragma unroll
  for (int j = 0; j < 8; ++j) {
    tile[cb + j * 4 + 0][hl] = v[j].x;
    tile[cb + j * 4 + 1][hl] = v[j].y;
    tile[cb + j * 4 + 2][hl] = v[j].z;
    tile[cb + j * 4 + 3][hl] = v[j].w;
  }
  __syncthreads();
  const int cl = tid >> 2, hb = (tid & 3) * 32;
  const int cp = colp_of(c0 + cl);
  const float inv = 127.f / __int_as_float(swc_i[e * 1024 + cp]);
  i8 out[32];
#pragma unroll
  for (int k = 0; k < 32; ++k) out[k] = (i8)q8(tile[cl][hb + k], inv);
  i8* dst = &wguq[((size_t)e * 1024 + cp) * 1024 + h0 + hb];
  *(int4*)dst = *(int4*)out;
  *(int4*)(dst + 16) = *(int4*)(out + 16);
}

// ---------------- deterministic counting scatter (256-aligned segments) --------
__global__ __launch_bounds__(512) void k_scatter(
    const int* __restrict__ eidx, int* __restrict__ btok, int* __restrict__ slotmap,
    int* __restrict__ seg, int* __restrict__ segcnt) {
  __shared__ int cnt_s[8];
  __shared__ int goff_s[9];
  const int e = threadIdx.x >> 6;
  const int l = threadIdx.x & 63;

  int c1 = 0;
  for (int c = 0; c < T_TOK / 64; ++c) {
    int v = eidx[c * 64 + l];
    c1 += __popcll(__ballot((v & 255) == e)) + __popcll(__ballot(((v >> 8) & 255) == e));
  }
  if (l == 0) cnt_s[e] = c1;
  __syncthreads();
  if (threadIdx.x == 0) {
    int off = 0;
    for (int k = 0; k < 8; ++k) { goff_s[k] = off; off += (cnt_s[k] + 255) & ~255; }
    goff_s[8] = off;
  }
  __syncthreads();
  const int base0 = goff_s[e];
  const int cnt_e = cnt_s[e];
  const unsigned long long below = (l == 63) ? ~0ull >> 1 : ((1ull << l) - 1);

  int base = base0;
  for (int c = 0; c < T_TOK / 64; ++c) {
    const int t = c * 64 + l;
    const int v = eidx[t];
    const unsigned long long ma = __ballot((v & 255) == e);
    const unsigned long long mb = __ballot(((v >> 8) & 255) == e);
    if ((v & 255) == e) {
      int s = base + __popcll(ma & below);
      btok[s] = t; slotmap[2 * t] = s;
    }
    if (((v >> 8) & 255) == e) {
      int s = base + __popcll(ma) + __popcll(mb & below);
      btok[s] = t; slotmap[2 * t + 1] = s;
    }
    base += __popcll(ma) + __popcll(mb);
  }
  for (int p = cnt_e + l; p < ((cnt_e + 255) & ~255); p += 64) btok[base0 + p] = 0;
  if (threadIdx.x < 9) seg[threadIdx.x] = goff_s[threadIdx.x];
  if (threadIdx.x < 8) segcnt[threadIdx.x] = cnt_s[threadIdx.x];
}

__device__ __forceinline__ bool seg_lookup(const int* __restrict__ seg,
                                           const int* __restrict__ segcnt,
                                           int brow, int& e) {
  if (brow >= RBASE) { e = 8; return true; }
  if (brow >= seg[8]) return false;
  e = 0;
#pragma unroll
  for (int k = 1; k < 8; ++k) if (brow >= seg[k]) e = k;
  return brow < seg[e] + segcnt[e];
}

// =================================================================================
// GEMM1 (int8): 256x256 tile, K-slot=128 i8, 8 waves 4M x 2N (per-wave 64x128).
// LDS 160 KiB: A 3-ring + B 2-ring. Counted vmcnt(4), ^(row&7) swizzle.
// =================================================================================

#define G1_STG_A(kt) do { i8* _d = Alds + ((kt) % 3) * 32768 + w * 1024; \
    STAGE(sA0 + (kt) * 128, _d);                                         \
    STAGE(sA1 + (kt) * 128, _d + 8192);                                  \
    STAGE(sA2 + (kt) * 128, _d + 16384);                                 \
    STAGE(sA3 + (kt) * 128, _d + 24576); } while (0)
#define G1_STG_B(kt) do { i8* _d = Blds + ((kt) & 1) * 32768 + w * 1024; \
    STAGE(sB0 + (kt) * 128, _d);                                         \
    STAGE(sB1 + (kt) * 128, _d + 8192);                                  \
    STAGE(sB2 + (kt) * 128, _d + 16384);                                 \
    STAGE(sB3 + (kt) * 128, _d + 24576); } while (0)

#define G1_LOADF(AR, BR, KX) do {                                        \
    _Pragma("unroll") for (int m = 0; m < 4; ++m)                        \
      fA[m] = *(const i32x4*)&Alds[(AR) * 32768 + aBase + m * 2048 + (KX)]; \
    _Pragma("unroll") for (int n = 0; n < 8; ++n)                        \
      fB[n] = *(const i32x4*)&Blds[(BR) * 32768 + bBase + n * 2048 + (KX)]; } while (0)

#define G1_MFMA do { __builtin_amdgcn_s_setprio(1);                      \
    _Pragma("unroll") for (int m = 0; m < 4; ++m)                        \
      _Pragma("unroll") for (int n = 0; n < 8; ++n)                      \
        acc[m][n] = __builtin_amdgcn_mfma_i32_16x16x64_i8(fA[m], fB[n], acc[m][n], 0, 0, 0); \
    __builtin_amdgcn_s_setprio(0); } while (0)

__global__ __launch_bounds__(512) void k_gemm_gu(
    const i8* __restrict__ xq, const i8* __restrict__ wguq,
    const int* __restrict__ seg, const int* __restrict__ segcnt,
    const int* __restrict__ btok, const float* __restrict__ sxg,
    const int* __restrict__ swc_i,
    u16* __restrict__ act)
{
  const int bid = blockIdx.x;
  const int brow = (bid % NROWB) * BM;
  const int bcol = (bid / NROWB) * 256;
  int e;
  if (!seg_lookup(seg, segcnt, brow, e)) return;

  __shared__ __align__(16) i8 lds[163840];
  i8* const Alds = lds;
  i8* const Blds = lds + 98304;

  const int tid = threadIdx.x;
  const int w = tid >> 6, l = tid & 63;
  const int wm = w >> 1, wn = w & 1;
  const int fr = l & 15, fg = l >> 4;

  const int rr = w * 8 + (l >> 3);
  const int sw = ((l & 7) ^ (l >> 3)) * 16;
  int tr[4];
#pragma unroll
  for (int j = 0; j < 4; ++j) {
    const int gr = brow + j * 64 + rr;
    tr[j] = (e < 8) ? btok[gr] : (gr - RBASE);
  }
  const i8* sA0 = xq + (size_t)tr[0] * HID + sw;
  const i8* sA1 = xq + (size_t)tr[1] * HID + sw;
  const i8* sA2 = xq + (size_t)tr[2] * HID + sw;
  const i8* sA3 = xq + (size_t)tr[3] * HID + sw;
  const i8* sB0 = wguq + ((size_t)e * 1024 + bcol + 0 * 64 + rr) * HID + sw;
  const i8* sB1 = wguq + ((size_t)e * 1024 + bcol + 1 * 64 + rr) * HID + sw;
  const i8* sB2 = wguq + ((size_t)e * 1024 + bcol + 2 * 64 + rr) * HID + sw;
  const i8* sB3 = wguq + ((size_t)e * 1024 + bcol + 3 * 64 + rr) * HID + sw;

  const int aBase = (wm * 64 + fr) * 128;
  const int bBase = (wn * 128 + fr) * 128;
  const int kx0 = (fg ^ (fr & 7)) * 16;
  const int kx1 = kx0 ^ 64;

  i32x4 acc[4][8];
#pragma unroll
  for (int m = 0; m < 4; ++m)
#pragma unroll
    for (int n = 0; n < 8; ++n) acc[m][n] = (i32x4){0, 0, 0, 0};
  i32x4 fA[4], fB[8];

  const int NKT = HID / 128;   // 8 slots
  G1_STG_A(0); G1_STG_B(0); G1_STG_A(1);
  asm volatile("s_waitcnt vmcnt(4)" ::: "memory");
  __builtin_amdgcn_s_barrier();
  for (int s = 0; s < NKT; ++s) {
    if (s + 1 < NKT) G1_STG_B(s + 1);
    if (s + 2 < NKT) G1_STG_A(s + 2);
    const int ar = s % 3, br = s & 1;
    G1_LOADF(ar, br, kx0);
    asm volatile("s_waitcnt lgkmcnt(0)" ::: "memory");
    __builtin_amdgcn_sched_barrier(0);
    G1_MFMA;
    G1_LOADF(ar, br, kx1);
    asm volatile("s_waitcnt lgkmcnt(0)" ::: "memory");
    __builtin_amdgcn_sched_barrier(0);
    G1_MFMA;
    if (s + 2 < NKT) { asm volatile("s_waitcnt vmcnt(4)" ::: "memory"); }
    else             { asm volatile("s_waitcnt vmcnt(0)" ::: "memory"); }
    __builtin_amdgcn_s_barrier();
  }

  float* sxl  = (float*)lds;
  float* swcl = (float*)(lds + 2048);
  if (tid < BM) {
    const int rrow = brow + tid;
    const int tk = (e < 8) ? btok[rrow] : (rrow - RBASE);
    sxl[tid] = sxg[tk];
  } else {
    swcl[tid - 256] = __int_as_float(swc_i[e * 1024 + bcol + (tid - 256)]) * (1.f / 127.f);
  }
  __syncthreads();

#pragma unroll
  for (int m = 0; m < 4; ++m) {
#pragma unroll
    for (int p = 0; p < 4; ++p) {
      const i32x4 gI = acc[m][2 * p], uI = acc[m][2 * p + 1];
      const int col = ((bcol + wn * 128) >> 1) + p * 16 + fr;
      const float swg = swcl[wn * 128 + p * 32 + fr];
      const float swu = swcl[wn * 128 + p * 32 + 16 + fr];
#pragma unroll
      for (int r = 0; r < 4; ++r) {
        const int row_l = wm * 64 + m * 16 + fg * 4 + r;
        const float sx = sxl[row_l];
        const float gate = (float)gI[r] * (sx * swg);
        const float up   = (float)uI[r] * (sx * swu);
        const float sv = gate / (1.f + __expf(-gate));
        act[(size_t)(brow + row_l) * ISZ + col] = f2bf(sv * up);
      }
    }
  }
}

// =================================================================================
// GEMM2 (bf16): mirror. K-slot=64 bf16, A 3-ring + B 2-ring, counted vmcnt(4).
// =================================================================================

#define G2_STG_A(kt) do { u16* _d = Alds2 + ((kt) % 3) * 16384 + w * 512; \
    STAGE(dA0 + (kt) * 64, _d);                                           \
    STAGE(dA1 + (kt) * 64, _d + 4096);                                    \
    STAGE(dA2 + (kt) * 64, _d + 8192);                                    \
    STAGE(dA3 + (kt) * 64, _d + 12288); } while (0)
#define G2_STG_B(kt) do { u16* _d = Blds2 + ((kt) & 1) * 16384 + w * 512; \
    STAGE(dB0 + (kt) * 64, _d);                                           \
    STAGE(dB1 + (kt) * 64, _d + 4096);                                    \
    STAGE(dB2 + (kt) * 64, _d + 8192);                                    \
    STAGE(dB3 + (kt) * 64, _d + 12288); } while (0)

#define G2_LOADF(AR, BR, KX) do {                                         \
    _Pragma("unroll") for (int m = 0; m < 4; ++m)                         \
      gA[m] = *(const short8*)&Alds2[(AR) * 16384 + aBase + m * 1024 + (KX)]; \
    _Pragma("unroll") for (int n = 0; n < 8; ++n)                         \
      gB[n] = *(const short8*)&Blds2[(BR) * 16384 + bBase + n * 1024 + (KX)]; } while (0)

#define G2_MFMA do { __builtin_amdgcn_s_setprio(1);                       \
    _Pragma("unroll") for (int m = 0; m < 4; ++m)                         \
      _Pragma("unroll") for (int n = 0; n < 8; ++n)                       \
        accf[m][n] = __builtin_amdgcn_mfma_f32_16x16x32_bf16(gA[m], gB[n], accf[m][n], 0, 0, 0); \
    __builtin_amdgcn_s_setprio(0); } while (0)

__global__ __launch_bounds__(512) void k_gemm_down(
    const u16* __restrict__ act, const u16* __restrict__ wdT,
    const int* __restrict__ seg, const int* __restrict__ segcnt,
    u16* __restrict__ tmp) {
  const int bid = blockIdx.x;
  const int brow = (bid % NROWB) * BM;
  const int bcol = (bid / NROWB) * 256;
  int e;
  if (!seg_lookup(seg, segcnt, brow, e)) return;

  __shared__ __align__(16) u16 lds2[81920];
  u16* const Alds2 = lds2;
  u16* const Blds2 = lds2 + 49152;

  const int tid = threadIdx.x;
  const int w = tid >> 6, l = tid & 63;
  const int wm = w >> 1, wn = w & 1;
  const int fr = l & 15, fg = l >> 4;

  const int rr = w * 8 + (l >> 3);
  const int sw = ((l & 7) ^ (l >> 3)) * 8;
  const u16* dA0 = act + (size_t)(brow + 0 * 64 + rr) * ISZ + sw;
  const u16* dA1 = act + (size_t)(brow + 1 * 64 + rr) * ISZ + sw;
  const u16* dA2 = act + (size_t)(brow + 2 * 64 + rr) * ISZ + sw;
  const u16* dA3 = act + (size_t)(brow + 3 * 64 + rr) * ISZ + sw;
  const u16* dB0 = wdT + ((size_t)e * 1024 + bcol + 0 * 64 + rr) * ISZ + sw;
  const u16* dB1 = wdT + ((size_t)e * 1024 + bcol + 1 * 64 + rr) * ISZ + sw;
  const u16* dB2 = wdT + ((size_t)e * 1024 + bcol + 2 * 64 + rr) * ISZ + sw;
  const u16* dB3 = wdT + ((size_t)e * 1024 + bcol + 3 * 64 + rr) * ISZ + sw;

  const int aBase = (wm * 64 + fr) * 64;
  const int bBase = (wn * 128 + fr) * 64;
  const int kx0 = (fg ^ (fr & 7)) * 8;
  const int kx1 = kx0 ^ 32;

  f32x4 accf[4][8];
#pragma unroll
  for (int m = 0; m < 4; ++m)
#pragma unroll
    for (int n = 0; n < 8; ++n) accf[m][n] = (f32x4){0.f, 0.f, 0.f, 0.f};
  short8 gA[4], gB[8];

  const int NKT = ISZ / 64;   // 8 slots
  G2_STG_A(0); G2_STG_B(0); G2_STG_A(1);
  asm volatile("s_waitcnt vmcnt(4)" ::: "memory");
  __builtin_amdgcn_s_barrier();
  for (int s = 0; s < NKT; ++s) {
    if (s + 1 < NKT) G2_STG_B(s + 1);
    if (s + 2 < NKT) G2_STG_A(s + 2);
    const int ar = s % 3, br = s & 1;
    G2_LOADF(ar, br, kx0);
    asm volatile("s_waitcnt lgkmcnt(0)" ::: "memory");
    __builtin_amdgcn_sched_barrier(0);
    G2_MFMA;
    G2_LOADF(ar, br, kx1);
    asm volatile("s_waitcnt lgkmcnt(0)" ::: "memory");
    __builtin_amdgcn_sched_barrier(0);
    G2_MFMA;
    if (s + 2 < NKT) { asm volatile("s_waitcnt vmcnt(4)" ::: "memory"); }
    else             { asm volatile("s_waitcnt vmcnt(0)" ::: "memory"); }
    __builtin_amdgcn_s_barrier();
  }

#pragma unroll
  for (int m = 0; m < 4; ++m) {
#pragma unroll
    for (int r = 0; r < 4; ++r) {
      const int row = brow + wm * 64 + m * 16 + fg * 4 + r;
#pragma unroll
      for (int n = 0; n < 8; ++n) {
        const int col = bcol + wn * 128 + n * 16 + fr;
        tmp[(size_t)row * HID + col] = f2bf(accf[m][n][r]);
      }
    }
  }
}

// ---------------- combine: out[t] = tmp[sh] + w0*tmp[s0] + w1*tmp[s1] -----------
__global__ __launch_bounds__(256) void k_combine(
    const u16* __restrict__ tmp, const int* __restrict__ slotmap,
    const float2* __restrict__ wts, float* __restrict__ out) {
  const int idx = blockIdx.x * 256 + threadIdx.x;
  const int t = idx >> 7;
  const int c = (idx & 127) << 3;
  const int s0 = slotmap[2 * t], s1 = slotmap[2 * t + 1];
  const float2 wv = wts[t];
  const short8 a = *(const short8*)(tmp + (size_t)s0 * HID + c);
  const short8 b = *(const short8*)(tmp + (size_t)s1 * HID + c);
  const short8 s = *(const short8*)(tmp + (size_t)(RBASE + t) * HID + c);
  float r[8];
#pragma unroll
  for (int j = 0; j < 8; ++j)
    r[j] = bf2f((u16)s[j]) + wv.x * bf2f((u16)a[j]) + wv.y * bf2f((u16)b[j]);
  float* po = out + (size_t)t * HID + c;
  *(float4*)po       = make_float4(r[0], r[1], r[2], r[3]);
  *(float4*)(po + 4) = make_float4(r[4], r[5], r[6], r[7]);
}

// ---------------- launch ----------------
extern "C" void kernel_launch(void* const* d_in, const int* in_sizes, int n_in,
                              void* d_out, int out_size, void* d_ws, size_t ws_size,
                              hipStream_t stream) {
  const float* x   = (const float*)d_in[0];
  const float* wg  = (const float*)d_in[1];
  const float* wgu = (const float*)d_in[2];
  const float* wdn = (const float*)d_in[3];
  const float* wsg = (const float*)d_in[4];
  const float* wsd = (const float*)d_in[5];
  float* out = (float*)d_out;

  char* ws = (char*)d_ws;
  i8*  xq    = (i8*)ws;   ws += (size_t)T_TOK * HID;
  i8*  wguq  = (i8*)ws;   ws += (size_t)NE * 1024 * HID;
  u16* wdT   = (u16*)ws;  ws += (size_t)NE * HID * ISZ * 2;
  u16* actb  = (u16*)ws;  ws += (size_t)NSLOT * ISZ * 2;
  u16* tmp   = (u16*)ws;  ws += (size_t)NSLOT * HID * 2;
  float* sxg = (float*)ws; ws += (size_t)T_TOK * 4;
  int* swc_i = (int*)ws;  ws += (size_t)NE * 1024 * 4;
  int* eidx  = (int*)ws;  ws += (size_t)T_TOK * 4;
  float2* wt = (float2*)ws; ws += (size_t)T_TOK * 8;
  int* btok  = (int*)ws;  ws += (size_t)RBASE * 4;
  int* smap  = (int*)ws;  ws += (size_t)2 * T_TOK * 4;
  int* seg   = (int*)ws;  ws += 16 * 4;
  int* segc  = (int*)ws;

  k_rw<<<NB_RTR + NB_WAM + NB_WDN, 256, 0, stream>>>(
      x, wg, wgu, wsg, wdn, wsd, xq, sxg, eidx, wt, swc_i, wdT);
  k_prep2<<<NB_WGUP, 256, 0, stream>>>(wgu, wsg, swc_i, wguq);
  k_scatter<<<1, 512, 0, stream>>>(eidx, btok, smap, seg, segc);
  k_gemm_gu<<<NROWB * 4, 512, 0, stream>>>(
      xq, wguq, seg, segc, btok, sxg, swc_i, actb);
  k_gemm_down<<<NROWB * 4, 512, 0, stream>>>(actb, wdT, seg, segc, tmp);
  k_combine<<<(T_TOK * HID / 8) / 256, 256, 0, stream>>>(tmp, smap, wt, out);
}